// Round 9
// baseline (404.596 us; speedup 1.0000x reference)
//
#include <hip/hip_runtime.h>
#include <hip/hip_bf16.h>

typedef __attribute__((ext_vector_type(8))) short  svec8;
typedef __attribute__((ext_vector_type(4))) short  svec4;
typedef __attribute__((ext_vector_type(8))) __bf16 bfvec8;
typedef __attribute__((ext_vector_type(4))) float  f32x4;
typedef __attribute__((ext_vector_type(2))) float  f32x2;
typedef __attribute__((ext_vector_type(4))) unsigned uvec4;

#define LN_EPS 1e-3f

__device__ __forceinline__ short f2bf(float f) {
  union { float f; unsigned u; } v; v.f = f;
  unsigned u = v.u;
  u += 0x7fff + ((u >> 16) & 1);   // round-to-nearest-even
  return (short)(u >> 16);
}

__device__ __forceinline__ unsigned pk2(float a, float b) {
  unsigned short ua = __builtin_bit_cast(unsigned short, (__bf16)a);
  unsigned short ub = __builtin_bit_cast(unsigned short, (__bf16)b);
  return (unsigned)ua | ((unsigned)ub << 16);
}

__device__ __forceinline__ f32x2 up2(unsigned w) {   // u32 of 2 bf16 -> f32x2
  f32x2 r;
  r[0] = __builtin_bit_cast(float, w << 16);
  r[1] = __builtin_bit_cast(float, w & 0xffff0000u);
  return r;
}

__device__ __forceinline__ f32x4 mfma16(svec8 a, svec8 b, f32x4 c) {
  return __builtin_amdgcn_mfma_f32_16x16x32_bf16(
      __builtin_bit_cast(bfvec8, a), __builtin_bit_cast(bfvec8, b), c, 0, 0, 0);
}

// ================= setup: pack 6 weights + CSR offsets + folded constants, ONE launch ====
__global__ __launch_bounds__(256) void setup_kernel(
    const float* __restrict__ pW1, const float* __restrict__ pW2,
    const float* __restrict__ pg1,
    const float* __restrict__ mW1, const float* __restrict__ mW2,
    const float* __restrict__ mW3,
    short* __restrict__ w1qp, short* __restrict__ w1mp,
    short* __restrict__ w2p,  short* __restrict__ mw1p,
    short* __restrict__ mw2p, short* __restrict__ mw3p,
    const int* __restrict__ row, int E, int N, int* __restrict__ off,
    const float* __restrict__ g1, const float* __restrict__ be1,
    const float* __restrict__ b2, const float* __restrict__ g2,
    const float* __restrict__ w3, const float* __restrict__ be2,
    const float* __restrict__ b3,
    float* __restrict__ s2, float* __restrict__ b2pv,
    float* __restrict__ gw, float* __restrict__ consts, int nboff)
{
  const int b = blockIdx.x;
  const int tid = threadIdx.x;
  if (b < 384) {                       // ---- pack weights: 6 * 16384 elems ----
    int idx = b * 256 + tid;
    int which = idx >> 14, p = idx & 16383;
    int j = p & 7, lane = (p >> 3) & 63, t = p >> 9;
    int nf = t & 7, ks = t >> 3;
    int k = ks * 32 + (lane >> 4) * 8 + j;
    int n = nf * 16 + (lane & 15);
    const float* src; short* dst; float scale = 1.f;
    switch (which) {
      case 0:  src = pW1;         dst = w1qp; break;
      case 1:  src = pW1 + 16384; dst = w1mp; break;
      case 2:  src = pW2;         dst = w2p; scale = pg1[k]; break;
      case 3:  src = mW1;         dst = mw1p; break;
      case 4:  src = mW2;         dst = mw2p; break;
      default: src = mW3;         dst = mw3p; break;
    }
    dst[p] = f2bf(scale * src[k * 128 + n]);
  } else if (b < 384 + nboff) {        // ---- CSR offsets via binary search ----
    int i = (b - 384) * 256 + tid;
    if (i > N) return;
    int lo = 0, hi = E;
    while (lo < hi) { int mid = (lo + hi) >> 1; if (row[mid] < i) lo = mid + 1; else hi = mid; }
    off[i] = lo;
  } else {                             // ---- folded constants ----
    __shared__ float tmp[256];
    int n = tid;
    if (n < 128) {
      float s = 0.f, bb = 0.f;
      for (int k = 0; k < 128; ++k) {
        float w = pW2[k * 128 + n];
        s  = fmaf(g1[k],  w, s);
        bb = fmaf(be1[k], w, bb);
      }
      s2[n]   = s;
      b2pv[n] = bb + b2[n];
      float g = g2[n] * w3[n];
      gw[n] = g;
      tmp[n]       = g;
      tmp[128 + n] = be2[n] * w3[n];
    }
    __syncthreads();
    if (n == 0) {
      float a = 0.f, c = 0.f;
      for (int i = 0; i < 128; ++i) { a += tmp[i]; c += tmp[128 + i]; }
      consts[0] = a;
      consts[1] = c + b3[0];
    }
  }
}

// ============ node kernel: blocks [0,nbm) = mem MLP (+ fused mwt proj); rest = query proj =
__global__ __launch_bounds__(256) void node_kernel(
    const float* __restrict__ mem, const float* __restrict__ query,
    const short* __restrict__ w1p, const short* __restrict__ w2p, const short* __restrict__ w3p,
    const short* __restrict__ wmp, const short* __restrict__ wqp,
    const float* __restrict__ b1v, const float* __restrict__ b2v, const float* __restrict__ b3v,
    const float* __restrict__ g1v, const float* __restrict__ be1v,
    const float* __restrict__ g2v, const float* __restrict__ be2v,
    const float* __restrict__ pb1,
    short* __restrict__ mhb, short* __restrict__ mwt, short* __restrict__ qwt,
    int N, int nbm)
{
  __shared__ short Xs[64 * 128];
  __shared__ short H1s[64 * 128];
  __shared__ float redA[4][64];
  __shared__ float redB[4][64];

  const int tid  = threadIdx.x;
  const int wv   = tid >> 6;
  const int lane = tid & 63;
  const int g16  = lane >> 4;
  const int l16  = lane & 15;
  const bool is_mem = (blockIdx.x < nbm);
  const int r0   = (is_mem ? blockIdx.x : blockIdx.x - nbm) * 64;
  const float* src = is_mem ? mem : query;

  #pragma unroll
  for (int it = 0; it < 8; ++it) {
    int c = tid + it * 256;
    int r = c >> 5;
    int part = c & 31;
    int gr = r0 + r; if (gr >= N) gr = N - 1;
    f32x4 v = *(const f32x4*)(src + (size_t)gr * 128 + part * 4);
    svec4 s;
    s[0] = f2bf(v[0]); s[1] = f2bf(v[1]); s[2] = f2bf(v[2]); s[3] = f2bf(v[3]);
    int b = (r * 256 + part * 8) ^ ((r & 7) << 4);
    *(svec4*)((char*)Xs + b) = s;
  }
  __syncthreads();

  const int nfb = wv * 2;
  const int col0 = wv * 32 + l16, col1 = col0 + 16;

  if (!is_mem) {
    f32x4 acc[4][2];
    #pragma unroll
    for (int mf = 0; mf < 4; ++mf) { f32x4 z = {0.f,0.f,0.f,0.f}; acc[mf][0] = z; acc[mf][1] = z; }
    #pragma unroll
    for (int ks = 0; ks < 4; ++ks) {
      svec8 bw0 = *(const svec8*)(wqp + (((ks * 8 + nfb + 0) * 64 + lane) << 3));
      svec8 bw1 = *(const svec8*)(wqp + (((ks * 8 + nfb + 1) * 64 + lane) << 3));
      #pragma unroll
      for (int mf = 0; mf < 4; ++mf) {
        int row = mf * 16 + l16;
        int byt = (row * 256 + ks * 64 + g16 * 16) ^ ((row & 7) << 4);
        svec8 a = *(const svec8*)((const char*)Xs + byt);
        acc[mf][0] = mfma16(a, bw0, acc[mf][0]);
        acc[mf][1] = mfma16(a, bw1, acc[mf][1]);
      }
    }
    float bi0 = pb1[col0], bi1 = pb1[col1];
    #pragma unroll
    for (int mf = 0; mf < 4; ++mf)
      #pragma unroll
      for (int r = 0; r < 4; ++r) {
        int rr = mf * 16 + g16 * 4 + r;
        int gr = r0 + rr;
        if (gr < N) {
          qwt[(size_t)gr * 128 + col0] = f2bf(acc[mf][0][r] + bi0);
          qwt[(size_t)gr * 128 + col1] = f2bf(acc[mf][1][r] + bi1);
        }
      }
    return;
  }

  f32x4 acc[4][2], accm[4][2];
  #pragma unroll
  for (int mf = 0; mf < 4; ++mf) {
    f32x4 z = {0.f,0.f,0.f,0.f};
    acc[mf][0] = z; acc[mf][1] = z; accm[mf][0] = z; accm[mf][1] = z;
  }
  #pragma unroll
  for (int ks = 0; ks < 4; ++ks) {
    svec8 bw0 = *(const svec8*)(w1p + (((ks * 8 + nfb + 0) * 64 + lane) << 3));
    svec8 bw1 = *(const svec8*)(w1p + (((ks * 8 + nfb + 1) * 64 + lane) << 3));
    svec8 bm0 = *(const svec8*)(wmp + (((ks * 8 + nfb + 0) * 64 + lane) << 3));
    svec8 bm1 = *(const svec8*)(wmp + (((ks * 8 + nfb + 1) * 64 + lane) << 3));
    #pragma unroll
    for (int mf = 0; mf < 4; ++mf) {
      int row = mf * 16 + l16;
      int byt = (row * 256 + ks * 64 + g16 * 16) ^ ((row & 7) << 4);
      svec8 a = *(const svec8*)((const char*)Xs + byt);
      acc[mf][0]  = mfma16(a, bw0, acc[mf][0]);
      acc[mf][1]  = mfma16(a, bw1, acc[mf][1]);
      accm[mf][0] = mfma16(a, bm0, accm[mf][0]);
      accm[mf][1] = mfma16(a, bm1, accm[mf][1]);
    }
  }
  #pragma unroll
  for (int mf = 0; mf < 4; ++mf)
    #pragma unroll
    for (int r = 0; r < 4; ++r) {
      int rr = mf * 16 + g16 * 4 + r;
      int gr = r0 + rr;
      if (gr < N) {
        mwt[(size_t)gr * 128 + col0] = f2bf(accm[mf][0][r]);
        mwt[(size_t)gr * 128 + col1] = f2bf(accm[mf][1][r]);
      }
    }

  float bi0 = b1v[col0], bi1 = b1v[col1];
  float ga0 = g1v[col0], ga1 = g1v[col1];
  float bb0 = be1v[col0], bb1 = be1v[col1];
  float y[4][2][4], ps[4][4], pq[4][4];
  #pragma unroll
  for (int mf = 0; mf < 4; ++mf)
    #pragma unroll
    for (int r = 0; r < 4; ++r) {
      float y0 = fmaxf(acc[mf][0][r] + bi0, 0.f);
      float y1 = fmaxf(acc[mf][1][r] + bi1, 0.f);
      y[mf][0][r] = y0; y[mf][1][r] = y1;
      ps[mf][r] = y0 + y1;
      pq[mf][r] = y0 * y0 + y1 * y1;
    }
  #pragma unroll
  for (int mk = 1; mk <= 8; mk <<= 1)
    #pragma unroll
    for (int mf = 0; mf < 4; ++mf)
      #pragma unroll
      for (int r = 0; r < 4; ++r) {
        ps[mf][r] += __shfl_xor(ps[mf][r], mk, 64);
        pq[mf][r] += __shfl_xor(pq[mf][r], mk, 64);
      }
  if (l16 == 0) {
    #pragma unroll
    for (int mf = 0; mf < 4; ++mf)
      #pragma unroll
      for (int r = 0; r < 4; ++r) {
        redA[wv][mf * 16 + g16 * 4 + r] = ps[mf][r];
        redB[wv][mf * 16 + g16 * 4 + r] = pq[mf][r];
      }
  }
  __syncthreads();
  #pragma unroll
  for (int mf = 0; mf < 4; ++mf)
    #pragma unroll
    for (int r = 0; r < 4; ++r) {
      int rr = mf * 16 + g16 * 4 + r;
      float s = redA[0][rr] + redA[1][rr] + redA[2][rr] + redA[3][rr];
      float q = redB[0][rr] + redB[1][rr] + redB[2][rr] + redB[3][rr];
      float mu = s * (1.f / 128.f);
      float var = fmaxf(q * (1.f / 128.f) - mu * mu, 0.f);
      float rstd = rsqrtf(var + LN_EPS);
      float z0 = (y[mf][0][r] - mu) * rstd * ga0 + bb0;
      float z1 = (y[mf][1][r] - mu) * rstd * ga1 + bb1;
      int by0 = (rr * 256 + col0 * 2) ^ ((rr & 7) << 4);
      int by1 = (rr * 256 + col1 * 2) ^ ((rr & 7) << 4);
      *(short*)((char*)H1s + by0) = f2bf(z0);
      *(short*)((char*)H1s + by1) = f2bf(z1);
    }
  __syncthreads();

  f32x4 acc2[4][2];
  #pragma unroll
  for (int mf = 0; mf < 4; ++mf) { f32x4 z = {0.f,0.f,0.f,0.f}; acc2[mf][0] = z; acc2[mf][1] = z; }
  #pragma unroll
  for (int ks = 0; ks < 4; ++ks) {
    svec8 bw0 = *(const svec8*)(w2p + (((ks * 8 + nfb + 0) * 64 + lane) << 3));
    svec8 bw1 = *(const svec8*)(w2p + (((ks * 8 + nfb + 1) * 64 + lane) << 3));
    #pragma unroll
    for (int mf = 0; mf < 4; ++mf) {
      int row = mf * 16 + l16;
      int byt = (row * 256 + ks * 64 + g16 * 16) ^ ((row & 7) << 4);
      svec8 a = *(const svec8*)((const char*)H1s + byt);
      acc2[mf][0] = mfma16(a, bw0, acc2[mf][0]);
      acc2[mf][1] = mfma16(a, bw1, acc2[mf][1]);
    }
  }

  float bi20 = b2v[col0], bi21 = b2v[col1];
  float ga20 = g2v[col0], ga21 = g2v[col1];
  float bb20 = be2v[col0], bb21 = be2v[col1];
  float y2[4][2][4];
  #pragma unroll
  for (int mf = 0; mf < 4; ++mf)
    #pragma unroll
    for (int r = 0; r < 4; ++r) {
      float y0 = fmaxf(acc2[mf][0][r] + bi20, 0.f);
      float y1 = fmaxf(acc2[mf][1][r] + bi21, 0.f);
      y2[mf][0][r] = y0; y2[mf][1][r] = y1;
      ps[mf][r] = y0 + y1;
      pq[mf][r] = y0 * y0 + y1 * y1;
    }
  #pragma unroll
  for (int mk = 1; mk <= 8; mk <<= 1)
    #pragma unroll
    for (int mf = 0; mf < 4; ++mf)
      #pragma unroll
      for (int r = 0; r < 4; ++r) {
        ps[mf][r] += __shfl_xor(ps[mf][r], mk, 64);
        pq[mf][r] += __shfl_xor(pq[mf][r], mk, 64);
      }
  if (l16 == 0) {
    #pragma unroll
    for (int mf = 0; mf < 4; ++mf)
      #pragma unroll
      for (int r = 0; r < 4; ++r) {
        redA[wv][mf * 16 + g16 * 4 + r] = ps[mf][r];
        redB[wv][mf * 16 + g16 * 4 + r] = pq[mf][r];
      }
  }
  __syncthreads();
  #pragma unroll
  for (int mf = 0; mf < 4; ++mf)
    #pragma unroll
    for (int r = 0; r < 4; ++r) {
      int rr = mf * 16 + g16 * 4 + r;
      float s = redA[0][rr] + redA[1][rr] + redA[2][rr] + redA[3][rr];
      float q = redB[0][rr] + redB[1][rr] + redB[2][rr] + redB[3][rr];
      float mu = s * (1.f / 128.f);
      float var = fmaxf(q * (1.f / 128.f) - mu * mu, 0.f);
      float rstd = rsqrtf(var + LN_EPS);
      float z0 = (y2[mf][0][r] - mu) * rstd * ga20 + bb20;
      float z1 = (y2[mf][1][r] - mu) * rstd * ga21 + bb21;
      int by0 = (rr * 256 + col0 * 2) ^ ((rr & 7) << 4);
      int by1 = (rr * 256 + col1 * 2) ^ ((rr & 7) << 4);
      *(short*)((char*)Xs + by0) = f2bf(z0);
      *(short*)((char*)Xs + by1) = f2bf(z1);
    }
  __syncthreads();

  f32x4 acc3[4][2];
  #pragma unroll
  for (int mf = 0; mf < 4; ++mf) { f32x4 z = {0.f,0.f,0.f,0.f}; acc3[mf][0] = z; acc3[mf][1] = z; }
  #pragma unroll
  for (int ks = 0; ks < 4; ++ks) {
    svec8 bw0 = *(const svec8*)(w3p + (((ks * 8 + nfb + 0) * 64 + lane) << 3));
    svec8 bw1 = *(const svec8*)(w3p + (((ks * 8 + nfb + 1) * 64 + lane) << 3));
    #pragma unroll
    for (int mf = 0; mf < 4; ++mf) {
      int row = mf * 16 + l16;
      int byt = (row * 256 + ks * 64 + g16 * 16) ^ ((row & 7) << 4);
      svec8 a = *(const svec8*)((const char*)Xs + byt);
      acc3[mf][0] = mfma16(a, bw0, acc3[mf][0]);
      acc3[mf][1] = mfma16(a, bw1, acc3[mf][1]);
    }
  }
  float bi30 = b3v[col0], bi31 = b3v[col1];
  #pragma unroll
  for (int mf = 0; mf < 4; ++mf)
    #pragma unroll
    for (int r = 0; r < 4; ++r) {
      int rr = mf * 16 + g16 * 4 + r;
      int gr = r0 + rr;
      if (gr < N) {
        mhb[(size_t)gr * 128 + col0] = f2bf(acc3[mf][0][r] + bi30);
        mhb[(size_t)gr * 128 + col1] = f2bf(acc3[mf][1][r] + bi31);
      }
    }
}

// ---- relu(q+m) with packed f32; emits B-frags + sum/sumsq ----
__device__ __forceinline__ void relu_stats(const svec8* qv, const svec8* mv,
                                           svec8* yf, float& ps_o, float& pq_o) {
  f32x2 psv = {0.f, 0.f}, pqv = {0.f, 0.f};
  #pragma unroll
  for (int ks2 = 0; ks2 < 4; ++ks2) {
    uvec4 qu = __builtin_bit_cast(uvec4, qv[ks2]);
    uvec4 mu = __builtin_bit_cast(uvec4, mv[ks2]);
    uvec4 u;
    #pragma unroll
    for (int p = 0; p < 4; ++p) {
      f32x2 y = __builtin_elementwise_max(up2(qu[p]) + up2(mu[p]), (f32x2){0.f, 0.f});
      psv += y;
      pqv += y * y;
      u[p] = pk2(y[0], y[1]);
    }
    yf[ks2] = __builtin_bit_cast(svec8, u);
  }
  float ps = psv[0] + psv[1], pq = pqv[0] + pqv[1];
  ps += __shfl_xor(ps, 16, 64); pq += __shfl_xor(pq, 16, 64);
  ps += __shfl_xor(ps, 32, 64); pq += __shfl_xor(pq, 32, 64);
  ps_o = ps; pq_o = pq;
}

// ---- folded LN1 affine + bias + relu + folded LN2+layer3 + tanh, packed f32 ----
__device__ __forceinline__ void epilogue(const f32x4* acc2, float rstd1, float mu1,
    const float* s2v, const float* b2pv, const float* gwv, float Sgw, float cb,
    float* __restrict__ hout, int e, bool valid, int lane, int g) {
  f32x2 rst = {rstd1, rstd1};
  f32x2 nmu = {-rstd1 * mu1, -rstd1 * mu1};
  f32x2 psv = {0.f,0.f}, pqv = {0.f,0.f}, pwv = {0.f,0.f};
  #pragma unroll
  for (int nf = 0; nf < 8; ++nf) {
    f32x4 s2 = *(const f32x4*)(s2v  + nf * 16 + g * 4);
    f32x4 bb = *(const f32x4*)(b2pv + nf * 16 + g * 4);
    f32x4 gw = *(const f32x4*)(gwv  + nf * 16 + g * 4);
    #pragma unroll
    for (int p = 0; p < 2; ++p) {
      f32x2 a   = { acc2[nf][2*p], acc2[nf][2*p+1] };
      f32x2 s2p = { s2[2*p], s2[2*p+1] };
      f32x2 bbp = { bb[2*p], bb[2*p+1] };
      f32x2 gwp = { gw[2*p], gw[2*p+1] };
      f32x2 h = rst * a + (nmu * s2p + bbp);
      f32x2 y = __builtin_elementwise_max(h, (f32x2){0.f, 0.f});
      psv += y;
      pqv += y * y;
      pwv += y * gwp;
    }
  }
  float ps2 = psv[0] + psv[1], pq2 = pqv[0] + pqv[1], pw2 = pwv[0] + pwv[1];
  ps2 += __shfl_xor(ps2, 16, 64); pq2 += __shfl_xor(pq2, 16, 64); pw2 += __shfl_xor(pw2, 16, 64);
  ps2 += __shfl_xor(ps2, 32, 64); pq2 += __shfl_xor(pq2, 32, 64); pw2 += __shfl_xor(pw2, 32, 64);
  float mu2   = ps2 * (1.f / 128.f);
  float var2  = fmaxf(pq2 * (1.f / 128.f) - mu2 * mu2, 0.f);
  float rstd2 = rsqrtf(var2 + LN_EPS);
  float p3 = fmaf(rstd2, pw2 - mu2 * Sgw, cb);
  if (lane < 16 && valid) hout[e] = tanhf(p3);
}

// ---- double-buffered edge tile state ----
struct EdgeBuf {
  svec8 q0[4], m0[4], q1[4], m1[4];
  int e0, e1;
  bool v0, v1;
};

__device__ __forceinline__ void edge_load(EdgeBuf& B, int tile, int wv, int l16, int g,
    const int* __restrict__ rowi, const int* __restrict__ coli,
    const short* __restrict__ qwt, const short* __restrict__ mwt, int E) {
  int eb = tile * 128 + wv * 32;
  B.e0 = eb + l16; B.e1 = eb + 16 + l16;
  B.v0 = (B.e0 < E); B.v1 = (B.e1 < E);
  int ee0 = B.v0 ? B.e0 : 0, ee1 = B.v1 ? B.e1 : 0;
  const short* q0 = qwt + (size_t)rowi[ee0] * 128 + g * 8;
  const short* m0 = mwt + (size_t)coli[ee0] * 128 + g * 8;
  const short* q1 = qwt + (size_t)rowi[ee1] * 128 + g * 8;
  const short* m1 = mwt + (size_t)coli[ee1] * 128 + g * 8;
  #pragma unroll
  for (int ks2 = 0; ks2 < 4; ++ks2) {
    B.q0[ks2] = *(const svec8*)(q0 + ks2 * 32);
    B.m0[ks2] = *(const svec8*)(m0 + ks2 * 32);
    B.q1[ks2] = *(const svec8*)(q1 + ks2 * 32);
    B.m1[ks2] = *(const svec8*)(m1 + ks2 * 32);
  }
}

__device__ __forceinline__ void edge_process(const EdgeBuf& B, const short* __restrict__ w2s,
    const float* __restrict__ s2v, const float* __restrict__ b2pv,
    const float* __restrict__ gwv, float Sgw, float cb,
    float* __restrict__ hout, int lane, int g) {
  svec8 yf0[4], yf1[4];
  float ps0, pq0, ps1, pq1;
  relu_stats(B.q0, B.m0, yf0, ps0, pq0);
  relu_stats(B.q1, B.m1, yf1, ps1, pq1);
  float mu1_0   = ps0 * (1.f / 128.f);
  float rstd1_0 = rsqrtf(fmaxf(pq0 * (1.f / 128.f) - mu1_0 * mu1_0, 0.f) + LN_EPS);
  float mu1_1   = ps1 * (1.f / 128.f);
  float rstd1_1 = rsqrtf(fmaxf(pq1 * (1.f / 128.f) - mu1_1 * mu1_1, 0.f) + LN_EPS);

  f32x4 acc2a[8], acc2b[8];
  #pragma unroll
  for (int nf = 0; nf < 8; ++nf) { f32x4 z = {0.f,0.f,0.f,0.f}; acc2a[nf] = z; acc2b[nf] = z; }
  #pragma unroll
  for (int ks2 = 0; ks2 < 4; ++ks2) {
    #pragma unroll
    for (int nf = 0; nf < 8; ++nf) {
      svec8 w = *(const svec8*)(w2s + (((ks2 * 8 + nf) * 64 + lane) << 3));
      acc2a[nf] = mfma16(w, yf0[ks2], acc2a[nf]);
      acc2b[nf] = mfma16(w, yf1[ks2], acc2b[nf]);
    }
  }
  epilogue(acc2a, rstd1_0, mu1_0, s2v, b2pv, gwv, Sgw, cb, hout, B.e0, B.v0, lane, g);
  epilogue(acc2b, rstd1_1, mu1_1, s2v, b2pv, gwv, Sgw, cb, hout, B.e1, B.v1, lane, g);
}

// ------- edge MLP: persistent blocks, chunked tiles, double-buffered gather pipeline -------
__global__ __launch_bounds__(256, 2) void edge_mlp_kernel(
    const short* __restrict__ qwt, const short* __restrict__ mwt,
    const int* __restrict__ rowi, const int* __restrict__ coli,
    const short* __restrict__ w2p,
    const float* __restrict__ s2v, const float* __restrict__ b2pv,
    const float* __restrict__ gwv, const float* __restrict__ consts,
    float* __restrict__ hout, int E, int ntiles)
{
  __shared__ short w2s[16384];   // 32 KB: all W2' fragments

  const int tid  = threadIdx.x;
  const int wv   = tid >> 6;
  const int lane = tid & 63;
  const int g    = lane >> 4;
  const int l16  = lane & 15;

  // XCD swizzle (gridDim.x divisible by 8) then contiguous tile chunk per block
  const int nb  = gridDim.x;
  const int bid = (blockIdx.x & 7) * (nb >> 3) + (blockIdx.x >> 3);
  const int t0  = (int)((long long)bid * ntiles / nb);
  const int t1  = (int)((long long)(bid + 1) * ntiles / nb);

  // stage W2' fragments (linear copy)
  #pragma unroll
  for (int it = 0; it < 8; ++it) {
    int o = (it * 256 + tid) * 8;    // shorts
    *(f32x4*)(w2s + o) = *(const f32x4*)(w2p + o);
  }
  __syncthreads();

  const float Sgw = consts[0], cb = consts[1];

  EdgeBuf A, B;
  int t = t0;
  if (t < t1) edge_load(A, t, wv, l16, g, rowi, coli, qwt, mwt, E);
  while (t < t1) {
    if (t + 1 < t1) edge_load(B, t + 1, wv, l16, g, rowi, coli, qwt, mwt, E);
    edge_process(A, w2s, s2v, b2pv, gwv, Sgw, cb, hout, lane, g);
    ++t;
    if (t >= t1) break;
    if (t + 1 < t1) edge_load(A, t + 1, wv, l16, g, rowi, coli, qwt, mwt, E);
    edge_process(B, w2s, s2v, b2pv, gwv, Sgw, cb, hout, lane, g);
    ++t;
  }
}

// ---------------- segment sum: full wave per node, 8 edges in flight ----------------
__global__ __launch_bounds__(256) void segsum_kernel(
    const int* __restrict__ off, const int* __restrict__ coli,
    const float* __restrict__ hbuf, const short* __restrict__ mhb,
    float* __restrict__ out, int N)
{
  int wv = threadIdx.x >> 6, lane = threadIdx.x & 63;
  int i = blockIdx.x * 4 + wv;
  if (i >= N) return;
  int s = off[i], e = off[i + 1];
  f32x2 acc = {0.f, 0.f};
  int k = s;
  for (; k + 8 <= e; k += 8) {
    float h[8]; unsigned w[8];
    #pragma unroll
    for (int u = 0; u < 8; ++u) {
      h[u] = hbuf[k + u];
      w[u] = *(const unsigned*)(mhb + (size_t)coli[k + u] * 128 + lane * 2);
    }
    #pragma unroll
    for (int u = 0; u < 8; ++u)
      acc += (f32x2){h[u], h[u]} * up2(w[u]);
  }
  for (; k < e; ++k) {
    float h = hbuf[k];
    unsigned w = *(const unsigned*)(mhb + (size_t)coli[k] * 128 + lane * 2);
    acc += (f32x2){h, h} * up2(w);
  }
  *(f32x2*)(out + (size_t)i * 128 + lane * 2) = acc;
}

extern "C" void kernel_launch(void* const* d_in, const int* in_sizes, int n_in,
                              void* d_out, int out_size, void* d_ws, size_t ws_size,
                              hipStream_t stream) {
  const float* query = (const float*)d_in[0];
  const float* mem   = (const float*)d_in[1];
  const int*   row   = (const int*)d_in[2];
  const int*   col   = (const int*)d_in[3];
  const float* pW1 = (const float*)d_in[4];  const float* pb1 = (const float*)d_in[5];
  const float* pW2 = (const float*)d_in[6];  const float* pb2 = (const float*)d_in[7];
  const float* pW3 = (const float*)d_in[8];  const float* pb3 = (const float*)d_in[9];
  const float* pg1 = (const float*)d_in[10]; const float* pbe1 = (const float*)d_in[11];
  const float* pg2 = (const float*)d_in[12]; const float* pbe2 = (const float*)d_in[13];
  const float* mW1 = (const float*)d_in[14]; const float* mb1 = (const float*)d_in[15];
  const float* mW2 = (const float*)d_in[16]; const float* mb2 = (const float*)d_in[17];
  const float* mW3 = (const float*)d_in[18]; const float* mb3 = (const float*)d_in[19];
  const float* mg1 = (const float*)d_in[20]; const float* mbe1 = (const float*)d_in[21];
  const float* mg2 = (const float*)d_in[22]; const float* mbe2 = (const float*)d_in[23];

  const int N = in_sizes[0] / 128;
  const int E = in_sizes[2];

  char* ws = (char*)d_ws;
  short* w1qp = (short*)(ws + 0);        // 32768 B
  short* w1mp = (short*)(ws + 32768);    // 32768 B
  short* w2p  = (short*)(ws + 65536);    // 32768 B (scaled by g1)
  short* mw1p = (short*)(ws + 98304);    // 32768 B
  short* mw2p = (short*)(ws + 131072);   // 32768 B
  short* mw3p = (short*)(ws + 163840);   // 32768 B
  float* s2v  = (float*)(ws + 196608);   // 512 B
  float* b2pv = (float*)(ws + 197120);   // 512 B
  float* gwv  = (float*)(ws + 197632);   // 512 B
  float* cons = (float*)(ws + 198144);   // 64 B
  int*   offs = (int*)(ws + 198208);     // (N+1)*4
  size_t o = 198208 + (((size_t)(N + 1) * 4 + 255) / 256) * 256;
  short* qwt  = (short*)(ws + o);  o += (size_t)N * 128 * 2;   // bf16 q@W1t + b1
  short* mwt  = (short*)(ws + o);  o += (size_t)N * 128 * 2;   // bf16 m@W1b
  short* mhb  = (short*)(ws + o);  o += (size_t)N * 128 * 2;   // bf16 mem_head
  float* hbuf = (float*)(ws + o);  o += (size_t)E * 4;

  if (ws_size < o) return;

  const int nboff = (N + 1 + 255) / 256;
  setup_kernel<<<384 + nboff + 1, 256, 0, stream>>>(
      pW1, pW2, pg1, mW1, mW2, mW3, w1qp, w1mp, w2p, mw1p, mw2p, mw3p,
      row, E, N, offs,
      pg1, pbe1, pb2, pg2, pW3, pbe2, pb3, s2v, b2pv, gwv, cons, nboff);

  const int nbm = (N + 63) / 64;
  node_kernel<<<2 * nbm, 256, 0, stream>>>(
      mem, query, mw1p, mw2p, mw3p, w1mp, w1qp,
      mb1, mb2, mb3, mg1, mbe1, mg2, mbe2, pb1,
      mhb, mwt, qwt, N, nbm);

  const int ntiles = (E + 127) / 128;
  edge_mlp_kernel<<<512, 256, 0, stream>>>(
      qwt, mwt, row, col, w2p, s2v, b2pv, gwv, cons, hbuf, E, ntiles);

  segsum_kernel<<<(N + 3) / 4, 256, 0, stream>>>(offs, col, hbuf, mhb, (float*)d_out, N);
}

// Round 10
// 226.402 us; speedup vs baseline: 1.7871x; 1.7871x over previous
//
#include <hip/hip_runtime.h>
#include <hip/hip_bf16.h>

typedef __attribute__((ext_vector_type(8))) short  svec8;
typedef __attribute__((ext_vector_type(4))) short  svec4;
typedef __attribute__((ext_vector_type(8))) __bf16 bfvec8;
typedef __attribute__((ext_vector_type(4))) float  f32x4;
typedef __attribute__((ext_vector_type(2))) float  f32x2;
typedef __attribute__((ext_vector_type(4))) unsigned uvec4;

#define LN_EPS 1e-3f

__device__ __forceinline__ short f2bf(float f) {
  union { float f; unsigned u; } v; v.f = f;
  unsigned u = v.u;
  u += 0x7fff + ((u >> 16) & 1);   // round-to-nearest-even
  return (short)(u >> 16);
}

__device__ __forceinline__ unsigned pk2(float a, float b) {
  unsigned short ua = __builtin_bit_cast(unsigned short, (__bf16)a);
  unsigned short ub = __builtin_bit_cast(unsigned short, (__bf16)b);
  return (unsigned)ua | ((unsigned)ub << 16);
}

__device__ __forceinline__ f32x2 up2(unsigned w) {   // u32 of 2 bf16 -> f32x2
  f32x2 r;
  r[0] = __builtin_bit_cast(float, w << 16);
  r[1] = __builtin_bit_cast(float, w & 0xffff0000u);
  return r;
}

__device__ __forceinline__ f32x4 mfma16(svec8 a, svec8 b, f32x4 c) {
  return __builtin_amdgcn_mfma_f32_16x16x32_bf16(
      __builtin_bit_cast(bfvec8, a), __builtin_bit_cast(bfvec8, b), c, 0, 0, 0);
}

// ================= setup: pack 6 weights + CSR offsets + folded constants, ONE launch ====
__global__ __launch_bounds__(256) void setup_kernel(
    const float* __restrict__ pW1, const float* __restrict__ pW2,
    const float* __restrict__ pg1,
    const float* __restrict__ mW1, const float* __restrict__ mW2,
    const float* __restrict__ mW3,
    short* __restrict__ w1qp, short* __restrict__ w1mp,
    short* __restrict__ w2p,  short* __restrict__ mw1p,
    short* __restrict__ mw2p, short* __restrict__ mw3p,
    const int* __restrict__ row, int E, int N, int* __restrict__ off,
    const float* __restrict__ g1, const float* __restrict__ be1,
    const float* __restrict__ b2, const float* __restrict__ g2,
    const float* __restrict__ w3, const float* __restrict__ be2,
    const float* __restrict__ b3,
    float* __restrict__ s2, float* __restrict__ b2pv,
    float* __restrict__ gw, float* __restrict__ consts, int nboff)
{
  const int b = blockIdx.x;
  const int tid = threadIdx.x;
  if (b < 384) {                       // ---- pack weights: 6 * 16384 elems ----
    int idx = b * 256 + tid;
    int which = idx >> 14, p = idx & 16383;
    int j = p & 7, lane = (p >> 3) & 63, t = p >> 9;
    int nf = t & 7, ks = t >> 3;
    int k = ks * 32 + (lane >> 4) * 8 + j;
    int n = nf * 16 + (lane & 15);
    const float* src; short* dst; float scale = 1.f;
    switch (which) {
      case 0:  src = pW1;         dst = w1qp; break;
      case 1:  src = pW1 + 16384; dst = w1mp; break;
      case 2:  src = pW2;         dst = w2p; scale = pg1[k]; break;
      case 3:  src = mW1;         dst = mw1p; break;
      case 4:  src = mW2;         dst = mw2p; break;
      default: src = mW3;         dst = mw3p; break;
    }
    dst[p] = f2bf(scale * src[k * 128 + n]);
  } else if (b < 384 + nboff) {        // ---- CSR offsets via binary search ----
    int i = (b - 384) * 256 + tid;
    if (i > N) return;
    int lo = 0, hi = E;
    while (lo < hi) { int mid = (lo + hi) >> 1; if (row[mid] < i) lo = mid + 1; else hi = mid; }
    off[i] = lo;
  } else {                             // ---- folded constants ----
    __shared__ float tmp[256];
    int n = tid;
    if (n < 128) {
      float s = 0.f, bb = 0.f;
      for (int k = 0; k < 128; ++k) {
        float w = pW2[k * 128 + n];
        s  = fmaf(g1[k],  w, s);
        bb = fmaf(be1[k], w, bb);
      }
      s2[n]   = s;
      b2pv[n] = bb + b2[n];
      float g = g2[n] * w3[n];
      gw[n] = g;
      tmp[n]       = g;
      tmp[128 + n] = be2[n] * w3[n];
    }
    __syncthreads();
    if (n == 0) {
      float a = 0.f, c = 0.f;
      for (int i = 0; i < 128; ++i) { a += tmp[i]; c += tmp[128 + i]; }
      consts[0] = a;
      consts[1] = c + b3[0];
    }
  }
}

// ============ node kernel: blocks [0,nbm) = mem MLP (+ fused mwt proj); rest = query proj =
__global__ __launch_bounds__(256) void node_kernel(
    const float* __restrict__ mem, const float* __restrict__ query,
    const short* __restrict__ w1p, const short* __restrict__ w2p, const short* __restrict__ w3p,
    const short* __restrict__ wmp, const short* __restrict__ wqp,
    const float* __restrict__ b1v, const float* __restrict__ b2v, const float* __restrict__ b3v,
    const float* __restrict__ g1v, const float* __restrict__ be1v,
    const float* __restrict__ g2v, const float* __restrict__ be2v,
    const float* __restrict__ pb1,
    short* __restrict__ mhb, short* __restrict__ mwt, short* __restrict__ qwt,
    int N, int nbm)
{
  __shared__ short Xs[64 * 128];
  __shared__ short H1s[64 * 128];
  __shared__ float redA[4][64];
  __shared__ float redB[4][64];

  const int tid  = threadIdx.x;
  const int wv   = tid >> 6;
  const int lane = tid & 63;
  const int g16  = lane >> 4;
  const int l16  = lane & 15;
  const bool is_mem = (blockIdx.x < nbm);
  const int r0   = (is_mem ? blockIdx.x : blockIdx.x - nbm) * 64;
  const float* src = is_mem ? mem : query;

  #pragma unroll
  for (int it = 0; it < 8; ++it) {
    int c = tid + it * 256;
    int r = c >> 5;
    int part = c & 31;
    int gr = r0 + r; if (gr >= N) gr = N - 1;
    f32x4 v = *(const f32x4*)(src + (size_t)gr * 128 + part * 4);
    svec4 s;
    s[0] = f2bf(v[0]); s[1] = f2bf(v[1]); s[2] = f2bf(v[2]); s[3] = f2bf(v[3]);
    int b = (r * 256 + part * 8) ^ ((r & 7) << 4);
    *(svec4*)((char*)Xs + b) = s;
  }
  __syncthreads();

  const int nfb = wv * 2;
  const int col0 = wv * 32 + l16, col1 = col0 + 16;

  if (!is_mem) {
    f32x4 acc[4][2];
    #pragma unroll
    for (int mf = 0; mf < 4; ++mf) { f32x4 z = {0.f,0.f,0.f,0.f}; acc[mf][0] = z; acc[mf][1] = z; }
    #pragma unroll
    for (int ks = 0; ks < 4; ++ks) {
      svec8 bw0 = *(const svec8*)(wqp + (((ks * 8 + nfb + 0) * 64 + lane) << 3));
      svec8 bw1 = *(const svec8*)(wqp + (((ks * 8 + nfb + 1) * 64 + lane) << 3));
      #pragma unroll
      for (int mf = 0; mf < 4; ++mf) {
        int row = mf * 16 + l16;
        int byt = (row * 256 + ks * 64 + g16 * 16) ^ ((row & 7) << 4);
        svec8 a = *(const svec8*)((const char*)Xs + byt);
        acc[mf][0] = mfma16(a, bw0, acc[mf][0]);
        acc[mf][1] = mfma16(a, bw1, acc[mf][1]);
      }
    }
    float bi0 = pb1[col0], bi1 = pb1[col1];
    #pragma unroll
    for (int mf = 0; mf < 4; ++mf)
      #pragma unroll
      for (int r = 0; r < 4; ++r) {
        int rr = mf * 16 + g16 * 4 + r;
        int gr = r0 + rr;
        if (gr < N) {
          qwt[(size_t)gr * 128 + col0] = f2bf(acc[mf][0][r] + bi0);
          qwt[(size_t)gr * 128 + col1] = f2bf(acc[mf][1][r] + bi1);
        }
      }
    return;
  }

  f32x4 acc[4][2], accm[4][2];
  #pragma unroll
  for (int mf = 0; mf < 4; ++mf) {
    f32x4 z = {0.f,0.f,0.f,0.f};
    acc[mf][0] = z; acc[mf][1] = z; accm[mf][0] = z; accm[mf][1] = z;
  }
  #pragma unroll
  for (int ks = 0; ks < 4; ++ks) {
    svec8 bw0 = *(const svec8*)(w1p + (((ks * 8 + nfb + 0) * 64 + lane) << 3));
    svec8 bw1 = *(const svec8*)(w1p + (((ks * 8 + nfb + 1) * 64 + lane) << 3));
    svec8 bm0 = *(const svec8*)(wmp + (((ks * 8 + nfb + 0) * 64 + lane) << 3));
    svec8 bm1 = *(const svec8*)(wmp + (((ks * 8 + nfb + 1) * 64 + lane) << 3));
    #pragma unroll
    for (int mf = 0; mf < 4; ++mf) {
      int row = mf * 16 + l16;
      int byt = (row * 256 + ks * 64 + g16 * 16) ^ ((row & 7) << 4);
      svec8 a = *(const svec8*)((const char*)Xs + byt);
      acc[mf][0]  = mfma16(a, bw0, acc[mf][0]);
      acc[mf][1]  = mfma16(a, bw1, acc[mf][1]);
      accm[mf][0] = mfma16(a, bm0, accm[mf][0]);
      accm[mf][1] = mfma16(a, bm1, accm[mf][1]);
    }
  }
  #pragma unroll
  for (int mf = 0; mf < 4; ++mf)
    #pragma unroll
    for (int r = 0; r < 4; ++r) {
      int rr = mf * 16 + g16 * 4 + r;
      int gr = r0 + rr;
      if (gr < N) {
        mwt[(size_t)gr * 128 + col0] = f2bf(accm[mf][0][r]);
        mwt[(size_t)gr * 128 + col1] = f2bf(accm[mf][1][r]);
      }
    }

  float bi0 = b1v[col0], bi1 = b1v[col1];
  float ga0 = g1v[col0], ga1 = g1v[col1];
  float bb0 = be1v[col0], bb1 = be1v[col1];
  float y[4][2][4], ps[4][4], pq[4][4];
  #pragma unroll
  for (int mf = 0; mf < 4; ++mf)
    #pragma unroll
    for (int r = 0; r < 4; ++r) {
      float y0 = fmaxf(acc[mf][0][r] + bi0, 0.f);
      float y1 = fmaxf(acc[mf][1][r] + bi1, 0.f);
      y[mf][0][r] = y0; y[mf][1][r] = y1;
      ps[mf][r] = y0 + y1;
      pq[mf][r] = y0 * y0 + y1 * y1;
    }
  #pragma unroll
  for (int mk = 1; mk <= 8; mk <<= 1)
    #pragma unroll
    for (int mf = 0; mf < 4; ++mf)
      #pragma unroll
      for (int r = 0; r < 4; ++r) {
        ps[mf][r] += __shfl_xor(ps[mf][r], mk, 64);
        pq[mf][r] += __shfl_xor(pq[mf][r], mk, 64);
      }
  if (l16 == 0) {
    #pragma unroll
    for (int mf = 0; mf < 4; ++mf)
      #pragma unroll
      for (int r = 0; r < 4; ++r) {
        redA[wv][mf * 16 + g16 * 4 + r] = ps[mf][r];
        redB[wv][mf * 16 + g16 * 4 + r] = pq[mf][r];
      }
  }
  __syncthreads();
  #pragma unroll
  for (int mf = 0; mf < 4; ++mf)
    #pragma unroll
    for (int r = 0; r < 4; ++r) {
      int rr = mf * 16 + g16 * 4 + r;
      float s = redA[0][rr] + redA[1][rr] + redA[2][rr] + redA[3][rr];
      float q = redB[0][rr] + redB[1][rr] + redB[2][rr] + redB[3][rr];
      float mu = s * (1.f / 128.f);
      float var = fmaxf(q * (1.f / 128.f) - mu * mu, 0.f);
      float rstd = rsqrtf(var + LN_EPS);
      float z0 = (y[mf][0][r] - mu) * rstd * ga0 + bb0;
      float z1 = (y[mf][1][r] - mu) * rstd * ga1 + bb1;
      int by0 = (rr * 256 + col0 * 2) ^ ((rr & 7) << 4);
      int by1 = (rr * 256 + col1 * 2) ^ ((rr & 7) << 4);
      *(short*)((char*)H1s + by0) = f2bf(z0);
      *(short*)((char*)H1s + by1) = f2bf(z1);
    }
  __syncthreads();

  f32x4 acc2[4][2];
  #pragma unroll
  for (int mf = 0; mf < 4; ++mf) { f32x4 z = {0.f,0.f,0.f,0.f}; acc2[mf][0] = z; acc2[mf][1] = z; }
  #pragma unroll
  for (int ks = 0; ks < 4; ++ks) {
    svec8 bw0 = *(const svec8*)(w2p + (((ks * 8 + nfb + 0) * 64 + lane) << 3));
    svec8 bw1 = *(const svec8*)(w2p + (((ks * 8 + nfb + 1) * 64 + lane) << 3));
    #pragma unroll
    for (int mf = 0; mf < 4; ++mf) {
      int row = mf * 16 + l16;
      int byt = (row * 256 + ks * 64 + g16 * 16) ^ ((row & 7) << 4);
      svec8 a = *(const svec8*)((const char*)H1s + byt);
      acc2[mf][0] = mfma16(a, bw0, acc2[mf][0]);
      acc2[mf][1] = mfma16(a, bw1, acc2[mf][1]);
    }
  }

  float bi20 = b2v[col0], bi21 = b2v[col1];
  float ga20 = g2v[col0], ga21 = g2v[col1];
  float bb20 = be2v[col0], bb21 = be2v[col1];
  float y2[4][2][4];
  #pragma unroll
  for (int mf = 0; mf < 4; ++mf)
    #pragma unroll
    for (int r = 0; r < 4; ++r) {
      float y0 = fmaxf(acc2[mf][0][r] + bi20, 0.f);
      float y1 = fmaxf(acc2[mf][1][r] + bi21, 0.f);
      y2[mf][0][r] = y0; y2[mf][1][r] = y1;
      ps[mf][r] = y0 + y1;
      pq[mf][r] = y0 * y0 + y1 * y1;
    }
  #pragma unroll
  for (int mk = 1; mk <= 8; mk <<= 1)
    #pragma unroll
    for (int mf = 0; mf < 4; ++mf)
      #pragma unroll
      for (int r = 0; r < 4; ++r) {
        ps[mf][r] += __shfl_xor(ps[mf][r], mk, 64);
        pq[mf][r] += __shfl_xor(pq[mf][r], mk, 64);
      }
  if (l16 == 0) {
    #pragma unroll
    for (int mf = 0; mf < 4; ++mf)
      #pragma unroll
      for (int r = 0; r < 4; ++r) {
        redA[wv][mf * 16 + g16 * 4 + r] = ps[mf][r];
        redB[wv][mf * 16 + g16 * 4 + r] = pq[mf][r];
      }
  }
  __syncthreads();
  #pragma unroll
  for (int mf = 0; mf < 4; ++mf)
    #pragma unroll
    for (int r = 0; r < 4; ++r) {
      int rr = mf * 16 + g16 * 4 + r;
      float s = redA[0][rr] + redA[1][rr] + redA[2][rr] + redA[3][rr];
      float q = redB[0][rr] + redB[1][rr] + redB[2][rr] + redB[3][rr];
      float mu = s * (1.f / 128.f);
      float var = fmaxf(q * (1.f / 128.f) - mu * mu, 0.f);
      float rstd = rsqrtf(var + LN_EPS);
      float z0 = (y2[mf][0][r] - mu) * rstd * ga20 + bb20;
      float z1 = (y2[mf][1][r] - mu) * rstd * ga21 + bb21;
      int by0 = (rr * 256 + col0 * 2) ^ ((rr & 7) << 4);
      int by1 = (rr * 256 + col1 * 2) ^ ((rr & 7) << 4);
      *(short*)((char*)Xs + by0) = f2bf(z0);
      *(short*)((char*)Xs + by1) = f2bf(z1);
    }
  __syncthreads();

  f32x4 acc3[4][2];
  #pragma unroll
  for (int mf = 0; mf < 4; ++mf) { f32x4 z = {0.f,0.f,0.f,0.f}; acc3[mf][0] = z; acc3[mf][1] = z; }
  #pragma unroll
  for (int ks = 0; ks < 4; ++ks) {
    svec8 bw0 = *(const svec8*)(w3p + (((ks * 8 + nfb + 0) * 64 + lane) << 3));
    svec8 bw1 = *(const svec8*)(w3p + (((ks * 8 + nfb + 1) * 64 + lane) << 3));
    #pragma unroll
    for (int mf = 0; mf < 4; ++mf) {
      int row = mf * 16 + l16;
      int byt = (row * 256 + ks * 64 + g16 * 16) ^ ((row & 7) << 4);
      svec8 a = *(const svec8*)((const char*)Xs + byt);
      acc3[mf][0] = mfma16(a, bw0, acc3[mf][0]);
      acc3[mf][1] = mfma16(a, bw1, acc3[mf][1]);
    }
  }
  float bi30 = b3v[col0], bi31 = b3v[col1];
  #pragma unroll
  for (int mf = 0; mf < 4; ++mf)
    #pragma unroll
    for (int r = 0; r < 4; ++r) {
      int rr = mf * 16 + g16 * 4 + r;
      int gr = r0 + rr;
      if (gr < N) {
        mhb[(size_t)gr * 128 + col0] = f2bf(acc3[mf][0][r] + bi30);
        mhb[(size_t)gr * 128 + col1] = f2bf(acc3[mf][1][r] + bi31);
      }
    }
}

// ---- relu(q+m) with packed f32; emits B-frags + sum/sumsq ----
__device__ __forceinline__ void relu_stats(const svec8* qv, const svec8* mv,
                                           svec8* yf, float& ps_o, float& pq_o) {
  f32x2 psv = {0.f, 0.f}, pqv = {0.f, 0.f};
  #pragma unroll
  for (int ks2 = 0; ks2 < 4; ++ks2) {
    uvec4 qu = __builtin_bit_cast(uvec4, qv[ks2]);
    uvec4 mu = __builtin_bit_cast(uvec4, mv[ks2]);
    uvec4 u;
    #pragma unroll
    for (int p = 0; p < 4; ++p) {
      f32x2 y = __builtin_elementwise_max(up2(qu[p]) + up2(mu[p]), (f32x2){0.f, 0.f});
      psv += y;
      pqv += y * y;
      u[p] = pk2(y[0], y[1]);
    }
    yf[ks2] = __builtin_bit_cast(svec8, u);
  }
  float ps = psv[0] + psv[1], pq = pqv[0] + pqv[1];
  ps += __shfl_xor(ps, 16, 64); pq += __shfl_xor(pq, 16, 64);
  ps += __shfl_xor(ps, 32, 64); pq += __shfl_xor(pq, 32, 64);
  ps_o = ps; pq_o = pq;
}

// ---- folded LN1 affine + bias + relu + folded LN2+layer3 + tanh, packed f32 ----
__device__ __forceinline__ void epilogue(const f32x4* acc2, float rstd1, float mu1,
    const float* s2v, const float* b2pv, const float* gwv, float Sgw, float cb,
    float* __restrict__ hout, int e, bool valid, int lane, int g) {
  f32x2 rst = {rstd1, rstd1};
  f32x2 nmu = {-rstd1 * mu1, -rstd1 * mu1};
  f32x2 psv = {0.f,0.f}, pqv = {0.f,0.f}, pwv = {0.f,0.f};
  #pragma unroll
  for (int nf = 0; nf < 8; ++nf) {
    f32x4 s2 = *(const f32x4*)(s2v  + nf * 16 + g * 4);
    f32x4 bb = *(const f32x4*)(b2pv + nf * 16 + g * 4);
    f32x4 gw = *(const f32x4*)(gwv  + nf * 16 + g * 4);
    #pragma unroll
    for (int p = 0; p < 2; ++p) {
      f32x2 a   = { acc2[nf][2*p], acc2[nf][2*p+1] };
      f32x2 s2p = { s2[2*p], s2[2*p+1] };
      f32x2 bbp = { bb[2*p], bb[2*p+1] };
      f32x2 gwp = { gw[2*p], gw[2*p+1] };
      f32x2 h = rst * a + (nmu * s2p + bbp);
      f32x2 y = __builtin_elementwise_max(h, (f32x2){0.f, 0.f});
      psv += y;
      pqv += y * y;
      pwv += y * gwp;
    }
  }
  float ps2 = psv[0] + psv[1], pq2 = pqv[0] + pqv[1], pw2 = pwv[0] + pwv[1];
  ps2 += __shfl_xor(ps2, 16, 64); pq2 += __shfl_xor(pq2, 16, 64); pw2 += __shfl_xor(pw2, 16, 64);
  ps2 += __shfl_xor(ps2, 32, 64); pq2 += __shfl_xor(pq2, 32, 64); pw2 += __shfl_xor(pw2, 32, 64);
  float mu2   = ps2 * (1.f / 128.f);
  float var2  = fmaxf(pq2 * (1.f / 128.f) - mu2 * mu2, 0.f);
  float rstd2 = rsqrtf(var2 + LN_EPS);
  float p3 = fmaf(rstd2, pw2 - mu2 * Sgw, cb);
  if (lane < 16 && valid) hout[e] = tanhf(p3);
}

// ------- edge MLP: 512-thread blocks (8 waves share one 32KB W2' copy), EG=2 per wave -----
__global__ __launch_bounds__(512, 4) void edge_mlp_kernel(
    const short* __restrict__ qwt, const short* __restrict__ mwt,
    const int* __restrict__ rowi, const int* __restrict__ coli,
    const short* __restrict__ w2p,
    const float* __restrict__ s2v, const float* __restrict__ b2pv,
    const float* __restrict__ gwv, const float* __restrict__ consts,
    float* __restrict__ hout, int E)
{
  __shared__ short w2s[16384];   // 32 KB: all W2' fragments, shared by 8 waves

  const int tid  = threadIdx.x;
  const int wv   = tid >> 6;      // 0..7
  const int lane = tid & 63;
  const int g    = lane >> 4;
  const int l16  = lane & 15;

  // bijective XCD-aware block swizzle (m204)
  const int nb  = gridDim.x;
  const int q8  = nb >> 3, r8 = nb & 7;
  const int xcd = blockIdx.x & 7, sub = blockIdx.x >> 3;
  const int bid = (xcd < r8 ? xcd * (q8 + 1) : r8 * (q8 + 1) + (xcd - r8) * q8) + sub;

  // stage W2' fragments (linear copy, 512 threads x 16B x 4)
  #pragma unroll
  for (int it = 0; it < 4; ++it) {
    int o = (it * 512 + tid) * 8;    // shorts
    *(f32x4*)(w2s + o) = *(const f32x4*)(w2p + o);
  }
  __syncthreads();

  const int eb = bid * 256 + wv * 32;
  const int e0 = eb + l16, e1 = eb + 16 + l16;
  const bool v0 = (e0 < E), v1 = (e1 < E);
  const int ee0 = v0 ? e0 : 0, ee1 = v1 ? e1 : 0;
  const short* q0 = qwt + (size_t)rowi[ee0] * 128 + g * 8;
  const short* m0 = mwt + (size_t)coli[ee0] * 128 + g * 8;
  const short* q1 = qwt + (size_t)rowi[ee1] * 128 + g * 8;
  const short* m1 = mwt + (size_t)coli[ee1] * 128 + g * 8;

  // issue all 16 gathers up front
  svec8 qv0[4], mv0[4], qv1[4], mv1[4];
  #pragma unroll
  for (int ks2 = 0; ks2 < 4; ++ks2) {
    qv0[ks2] = *(const svec8*)(q0 + ks2 * 32);
    mv0[ks2] = *(const svec8*)(m0 + ks2 * 32);
    qv1[ks2] = *(const svec8*)(q1 + ks2 * 32);
    mv1[ks2] = *(const svec8*)(m1 + ks2 * 32);
  }

  svec8 yf0[4], yf1[4];
  float ps0, pq0, ps1, pq1;
  relu_stats(qv0, mv0, yf0, ps0, pq0);
  relu_stats(qv1, mv1, yf1, ps1, pq1);
  float mu1_0   = ps0 * (1.f / 128.f);
  float rstd1_0 = rsqrtf(fmaxf(pq0 * (1.f / 128.f) - mu1_0 * mu1_0, 0.f) + LN_EPS);
  float mu1_1   = ps1 * (1.f / 128.f);
  float rstd1_1 = rsqrtf(fmaxf(pq1 * (1.f / 128.f) - mu1_1 * mu1_1, 0.f) + LN_EPS);

  // layer 2 for both edge groups, sharing each W2' fragment read from LDS
  f32x4 acc2a[8], acc2b[8];
  #pragma unroll
  for (int nf = 0; nf < 8; ++nf) { f32x4 z = {0.f,0.f,0.f,0.f}; acc2a[nf] = z; acc2b[nf] = z; }
  #pragma unroll
  for (int ks2 = 0; ks2 < 4; ++ks2) {
    #pragma unroll
    for (int nf = 0; nf < 8; ++nf) {
      svec8 w = *(const svec8*)(w2s + (((ks2 * 8 + nf) * 64 + lane) << 3));
      acc2a[nf] = mfma16(w, yf0[ks2], acc2a[nf]);
      acc2b[nf] = mfma16(w, yf1[ks2], acc2b[nf]);
    }
  }

  float Sgw = consts[0], cb = consts[1];
  epilogue(acc2a, rstd1_0, mu1_0, s2v, b2pv, gwv, Sgw, cb, hout, e0, v0, lane, g);
  epilogue(acc2b, rstd1_1, mu1_1, s2v, b2pv, gwv, Sgw, cb, hout, e1, v1, lane, g);
}

// ---------------- segment sum: full wave per node, 8 edges in flight ----------------
__global__ __launch_bounds__(256) void segsum_kernel(
    const int* __restrict__ off, const int* __restrict__ coli,
    const float* __restrict__ hbuf, const short* __restrict__ mhb,
    float* __restrict__ out, int N)
{
  int wv = threadIdx.x >> 6, lane = threadIdx.x & 63;
  int i = blockIdx.x * 4 + wv;
  if (i >= N) return;
  int s = off[i], e = off[i + 1];
  f32x2 acc = {0.f, 0.f};
  int k = s;
  for (; k + 8 <= e; k += 8) {
    float h[8]; unsigned w[8];
    #pragma unroll
    for (int u = 0; u < 8; ++u) {
      h[u] = hbuf[k + u];
      w[u] = *(const unsigned*)(mhb + (size_t)coli[k + u] * 128 + lane * 2);
    }
    #pragma unroll
    for (int u = 0; u < 8; ++u)
      acc += (f32x2){h[u], h[u]} * up2(w[u]);
  }
  for (; k < e; ++k) {
    float h = hbuf[k];
    unsigned w = *(const unsigned*)(mhb + (size_t)coli[k] * 128 + lane * 2);
    acc += (f32x2){h, h} * up2(w);
  }
  *(f32x2*)(out + (size_t)i * 128 + lane * 2) = acc;
}

extern "C" void kernel_launch(void* const* d_in, const int* in_sizes, int n_in,
                              void* d_out, int out_size, void* d_ws, size_t ws_size,
                              hipStream_t stream) {
  const float* query = (const float*)d_in[0];
  const float* mem   = (const float*)d_in[1];
  const int*   row   = (const int*)d_in[2];
  const int*   col   = (const int*)d_in[3];
  const float* pW1 = (const float*)d_in[4];  const float* pb1 = (const float*)d_in[5];
  const float* pW2 = (const float*)d_in[6];  const float* pb2 = (const float*)d_in[7];
  const float* pW3 = (const float*)d_in[8];  const float* pb3 = (const float*)d_in[9];
  const float* pg1 = (const float*)d_in[10]; const float* pbe1 = (const float*)d_in[11];
  const float* pg2 = (const float*)d_in[12]; const float* pbe2 = (const float*)d_in[13];
  const float* mW1 = (const float*)d_in[14]; const float* mb1 = (const float*)d_in[15];
  const float* mW2 = (const float*)d_in[16]; const float* mb2 = (const float*)d_in[17];
  const float* mW3 = (const float*)d_in[18]; const float* mb3 = (const float*)d_in[19];
  const float* mg1 = (const float*)d_in[20]; const float* mbe1 = (const float*)d_in[21];
  const float* mg2 = (const float*)d_in[22]; const float* mbe2 = (const float*)d_in[23];

  const int N = in_sizes[0] / 128;
  const int E = in_sizes[2];

  char* ws = (char*)d_ws;
  short* w1qp = (short*)(ws + 0);        // 32768 B
  short* w1mp = (short*)(ws + 32768);    // 32768 B
  short* w2p  = (short*)(ws + 65536);    // 32768 B (scaled by g1)
  short* mw1p = (short*)(ws + 98304);    // 32768 B
  short* mw2p = (short*)(ws + 131072);   // 32768 B
  short* mw3p = (short*)(ws + 163840);   // 32768 B
  float* s2v  = (float*)(ws + 196608);   // 512 B
  float* b2pv = (float*)(ws + 197120);   // 512 B
  float* gwv  = (float*)(ws + 197632);   // 512 B
  float* cons = (float*)(ws + 198144);   // 64 B
  int*   offs = (int*)(ws + 198208);     // (N+1)*4
  size_t o = 198208 + (((size_t)(N + 1) * 4 + 255) / 256) * 256;
  short* qwt  = (short*)(ws + o);  o += (size_t)N * 128 * 2;   // bf16 q@W1t + b1
  short* mwt  = (short*)(ws + o);  o += (size_t)N * 128 * 2;   // bf16 m@W1b
  short* mhb  = (short*)(ws + o);  o += (size_t)N * 128 * 2;   // bf16 mem_head
  float* hbuf = (float*)(ws + o);  o += (size_t)E * 4;

  if (ws_size < o) return;

  const int nboff = (N + 1 + 255) / 256;
  setup_kernel<<<384 + nboff + 1, 256, 0, stream>>>(
      pW1, pW2, pg1, mW1, mW2, mW3, w1qp, w1mp, w2p, mw1p, mw2p, mw3p,
      row, E, N, offs,
      pg1, pbe1, pb2, pg2, pW3, pbe2, pb3, s2v, b2pv, gwv, cons, nboff);

  const int nbm = (N + 63) / 64;
  node_kernel<<<2 * nbm, 256, 0, stream>>>(
      mem, query, mw1p, mw2p, mw3p, w1mp, w1qp,
      mb1, mb2, mb3, mg1, mbe1, mg2, mbe2, pb1,
      mhb, mwt, qwt, N, nbm);

  edge_mlp_kernel<<<(E + 255) / 256, 512, 0, stream>>>(
      qwt, mwt, row, col, w2p, s2v, b2pv, gwv, cons, hbuf, E);

  segsum_kernel<<<(N + 3) / 4, 256, 0, stream>>>(offs, col, hbuf, mhb, (float*)d_out, N);
}

// Round 11
// 179.022 us; speedup vs baseline: 2.2600x; 1.2647x over previous
//
#include <hip/hip_runtime.h>
#include <hip/hip_bf16.h>

typedef __attribute__((ext_vector_type(8))) short  svec8;
typedef __attribute__((ext_vector_type(4))) short  svec4;
typedef __attribute__((ext_vector_type(8))) __bf16 bfvec8;
typedef __attribute__((ext_vector_type(4))) float  f32x4;
typedef __attribute__((ext_vector_type(2))) float  f32x2;
typedef __attribute__((ext_vector_type(4))) unsigned uvec4;

#define LN_EPS 1e-3f

__device__ __forceinline__ short f2bf(float f) {
  union { float f; unsigned u; } v; v.f = f;
  unsigned u = v.u;
  u += 0x7fff + ((u >> 16) & 1);   // round-to-nearest-even
  return (short)(u >> 16);
}

__device__ __forceinline__ unsigned pk2(float a, float b) {
  unsigned short ua = __builtin_bit_cast(unsigned short, (__bf16)a);
  unsigned short ub = __builtin_bit_cast(unsigned short, (__bf16)b);
  return (unsigned)ua | ((unsigned)ub << 16);
}

__device__ __forceinline__ f32x2 up2(unsigned w) {   // u32 of 2 bf16 -> f32x2
  f32x2 r;
  r[0] = __builtin_bit_cast(float, w << 16);
  r[1] = __builtin_bit_cast(float, w & 0xffff0000u);
  return r;
}

__device__ __forceinline__ f32x4 mfma16(svec8 a, svec8 b, f32x4 c) {
  return __builtin_amdgcn_mfma_f32_16x16x32_bf16(
      __builtin_bit_cast(bfvec8, a), __builtin_bit_cast(bfvec8, b), c, 0, 0, 0);
}

// ================= setup: pack 6 weights + CSR offsets + folded constants, ONE launch ====
__global__ __launch_bounds__(256) void setup_kernel(
    const float* __restrict__ pW1, const float* __restrict__ pW2,
    const float* __restrict__ pg1,
    const float* __restrict__ mW1, const float* __restrict__ mW2,
    const float* __restrict__ mW3,
    short* __restrict__ w1qp, short* __restrict__ w1mp,
    short* __restrict__ w2p,  short* __restrict__ mw1p,
    short* __restrict__ mw2p, short* __restrict__ mw3p,
    const int* __restrict__ row, int E, int N, int* __restrict__ off,
    const float* __restrict__ g1, const float* __restrict__ be1,
    const float* __restrict__ b2, const float* __restrict__ g2,
    const float* __restrict__ w3, const float* __restrict__ be2,
    const float* __restrict__ b3,
    float* __restrict__ s2, float* __restrict__ b2pv,
    float* __restrict__ gw, float* __restrict__ consts, int nboff)
{
  const int b = blockIdx.x;
  const int tid = threadIdx.x;
  if (b < 384) {                       // ---- pack weights: 6 * 16384 elems ----
    int idx = b * 256 + tid;
    int which = idx >> 14, p = idx & 16383;
    int j = p & 7, lane = (p >> 3) & 63, t = p >> 9;
    int nf = t & 7, ks = t >> 3;
    int k = ks * 32 + (lane >> 4) * 8 + j;
    int n = nf * 16 + (lane & 15);
    const float* src; short* dst; float scale = 1.f;
    switch (which) {
      case 0:  src = pW1;         dst = w1qp; break;
      case 1:  src = pW1 + 16384; dst = w1mp; break;
      case 2:  src = pW2;         dst = w2p; scale = pg1[k]; break;
      case 3:  src = mW1;         dst = mw1p; break;
      case 4:  src = mW2;         dst = mw2p; break;
      default: src = mW3;         dst = mw3p; break;
    }
    dst[p] = f2bf(scale * src[k * 128 + n]);
  } else if (b < 384 + nboff) {        // ---- CSR offsets via binary search ----
    int i = (b - 384) * 256 + tid;
    if (i > N) return;
    int lo = 0, hi = E;
    while (lo < hi) { int mid = (lo + hi) >> 1; if (row[mid] < i) lo = mid + 1; else hi = mid; }
    off[i] = lo;
  } else {                             // ---- folded constants ----
    __shared__ float tmp[256];
    int n = tid;
    if (n < 128) {
      float s = 0.f, bb = 0.f;
      for (int k = 0; k < 128; ++k) {
        float w = pW2[k * 128 + n];
        s  = fmaf(g1[k],  w, s);
        bb = fmaf(be1[k], w, bb);
      }
      s2[n]   = s;
      b2pv[n] = bb + b2[n];
      float g = g2[n] * w3[n];
      gw[n] = g;
      tmp[n]       = g;
      tmp[128 + n] = be2[n] * w3[n];
    }
    __syncthreads();
    if (n == 0) {
      float a = 0.f, c = 0.f;
      for (int i = 0; i < 128; ++i) { a += tmp[i]; c += tmp[128 + i]; }
      consts[0] = a;
      consts[1] = c + b3[0];
    }
  }
}

// ============ node kernel: blocks [0,nbm) = mem MLP (+ fused mwt proj); rest = query proj =
__global__ __launch_bounds__(256) void node_kernel(
    const float* __restrict__ mem, const float* __restrict__ query,
    const short* __restrict__ w1p, const short* __restrict__ w2p, const short* __restrict__ w3p,
    const short* __restrict__ wmp, const short* __restrict__ wqp,
    const float* __restrict__ b1v, const float* __restrict__ b2v, const float* __restrict__ b3v,
    const float* __restrict__ g1v, const float* __restrict__ be1v,
    const float* __restrict__ g2v, const float* __restrict__ be2v,
    const float* __restrict__ pb1,
    short* __restrict__ mhb, short* __restrict__ mwt, short* __restrict__ qwt,
    int N, int nbm)
{
  __shared__ short Xs[64 * 128];
  __shared__ short H1s[64 * 128];
  __shared__ float redA[4][64];
  __shared__ float redB[4][64];

  const int tid  = threadIdx.x;
  const int wv   = tid >> 6;
  const int lane = tid & 63;
  const int g16  = lane >> 4;
  const int l16  = lane & 15;
  const bool is_mem = (blockIdx.x < nbm);
  const int r0   = (is_mem ? blockIdx.x : blockIdx.x - nbm) * 64;
  const float* src = is_mem ? mem : query;

  #pragma unroll
  for (int it = 0; it < 8; ++it) {
    int c = tid + it * 256;
    int r = c >> 5;
    int part = c & 31;
    int gr = r0 + r; if (gr >= N) gr = N - 1;
    f32x4 v = *(const f32x4*)(src + (size_t)gr * 128 + part * 4);
    svec4 s;
    s[0] = f2bf(v[0]); s[1] = f2bf(v[1]); s[2] = f2bf(v[2]); s[3] = f2bf(v[3]);
    int b = (r * 256 + part * 8) ^ ((r & 7) << 4);
    *(svec4*)((char*)Xs + b) = s;
  }
  __syncthreads();

  const int nfb = wv * 2;
  const int col0 = wv * 32 + l16, col1 = col0 + 16;

  if (!is_mem) {
    f32x4 acc[4][2];
    #pragma unroll
    for (int mf = 0; mf < 4; ++mf) { f32x4 z = {0.f,0.f,0.f,0.f}; acc[mf][0] = z; acc[mf][1] = z; }
    #pragma unroll
    for (int ks = 0; ks < 4; ++ks) {
      svec8 bw0 = *(const svec8*)(wqp + (((ks * 8 + nfb + 0) * 64 + lane) << 3));
      svec8 bw1 = *(const svec8*)(wqp + (((ks * 8 + nfb + 1) * 64 + lane) << 3));
      #pragma unroll
      for (int mf = 0; mf < 4; ++mf) {
        int row = mf * 16 + l16;
        int byt = (row * 256 + ks * 64 + g16 * 16) ^ ((row & 7) << 4);
        svec8 a = *(const svec8*)((const char*)Xs + byt);
        acc[mf][0] = mfma16(a, bw0, acc[mf][0]);
        acc[mf][1] = mfma16(a, bw1, acc[mf][1]);
      }
    }
    float bi0 = pb1[col0], bi1 = pb1[col1];
    #pragma unroll
    for (int mf = 0; mf < 4; ++mf)
      #pragma unroll
      for (int r = 0; r < 4; ++r) {
        int rr = mf * 16 + g16 * 4 + r;
        int gr = r0 + rr;
        if (gr < N) {
          qwt[(size_t)gr * 128 + col0] = f2bf(acc[mf][0][r] + bi0);
          qwt[(size_t)gr * 128 + col1] = f2bf(acc[mf][1][r] + bi1);
        }
      }
    return;
  }

  f32x4 acc[4][2], accm[4][2];
  #pragma unroll
  for (int mf = 0; mf < 4; ++mf) {
    f32x4 z = {0.f,0.f,0.f,0.f};
    acc[mf][0] = z; acc[mf][1] = z; accm[mf][0] = z; accm[mf][1] = z;
  }
  #pragma unroll
  for (int ks = 0; ks < 4; ++ks) {
    svec8 bw0 = *(const svec8*)(w1p + (((ks * 8 + nfb + 0) * 64 + lane) << 3));
    svec8 bw1 = *(const svec8*)(w1p + (((ks * 8 + nfb + 1) * 64 + lane) << 3));
    svec8 bm0 = *(const svec8*)(wmp + (((ks * 8 + nfb + 0) * 64 + lane) << 3));
    svec8 bm1 = *(const svec8*)(wmp + (((ks * 8 + nfb + 1) * 64 + lane) << 3));
    #pragma unroll
    for (int mf = 0; mf < 4; ++mf) {
      int row = mf * 16 + l16;
      int byt = (row * 256 + ks * 64 + g16 * 16) ^ ((row & 7) << 4);
      svec8 a = *(const svec8*)((const char*)Xs + byt);
      acc[mf][0]  = mfma16(a, bw0, acc[mf][0]);
      acc[mf][1]  = mfma16(a, bw1, acc[mf][1]);
      accm[mf][0] = mfma16(a, bm0, accm[mf][0]);
      accm[mf][1] = mfma16(a, bm1, accm[mf][1]);
    }
  }
  #pragma unroll
  for (int mf = 0; mf < 4; ++mf)
    #pragma unroll
    for (int r = 0; r < 4; ++r) {
      int rr = mf * 16 + g16 * 4 + r;
      int gr = r0 + rr;
      if (gr < N) {
        mwt[(size_t)gr * 128 + col0] = f2bf(accm[mf][0][r]);
        mwt[(size_t)gr * 128 + col1] = f2bf(accm[mf][1][r]);
      }
    }

  float bi0 = b1v[col0], bi1 = b1v[col1];
  float ga0 = g1v[col0], ga1 = g1v[col1];
  float bb0 = be1v[col0], bb1 = be1v[col1];
  float y[4][2][4], ps[4][4], pq[4][4];
  #pragma unroll
  for (int mf = 0; mf < 4; ++mf)
    #pragma unroll
    for (int r = 0; r < 4; ++r) {
      float y0 = fmaxf(acc[mf][0][r] + bi0, 0.f);
      float y1 = fmaxf(acc[mf][1][r] + bi1, 0.f);
      y[mf][0][r] = y0; y[mf][1][r] = y1;
      ps[mf][r] = y0 + y1;
      pq[mf][r] = y0 * y0 + y1 * y1;
    }
  #pragma unroll
  for (int mk = 1; mk <= 8; mk <<= 1)
    #pragma unroll
    for (int mf = 0; mf < 4; ++mf)
      #pragma unroll
      for (int r = 0; r < 4; ++r) {
        ps[mf][r] += __shfl_xor(ps[mf][r], mk, 64);
        pq[mf][r] += __shfl_xor(pq[mf][r], mk, 64);
      }
  if (l16 == 0) {
    #pragma unroll
    for (int mf = 0; mf < 4; ++mf)
      #pragma unroll
      for (int r = 0; r < 4; ++r) {
        redA[wv][mf * 16 + g16 * 4 + r] = ps[mf][r];
        redB[wv][mf * 16 + g16 * 4 + r] = pq[mf][r];
      }
  }
  __syncthreads();
  #pragma unroll
  for (int mf = 0; mf < 4; ++mf)
    #pragma unroll
    for (int r = 0; r < 4; ++r) {
      int rr = mf * 16 + g16 * 4 + r;
      float s = redA[0][rr] + redA[1][rr] + redA[2][rr] + redA[3][rr];
      float q = redB[0][rr] + redB[1][rr] + redB[2][rr] + redB[3][rr];
      float mu = s * (1.f / 128.f);
      float var = fmaxf(q * (1.f / 128.f) - mu * mu, 0.f);
      float rstd = rsqrtf(var + LN_EPS);
      float z0 = (y[mf][0][r] - mu) * rstd * ga0 + bb0;
      float z1 = (y[mf][1][r] - mu) * rstd * ga1 + bb1;
      int by0 = (rr * 256 + col0 * 2) ^ ((rr & 7) << 4);
      int by1 = (rr * 256 + col1 * 2) ^ ((rr & 7) << 4);
      *(short*)((char*)H1s + by0) = f2bf(z0);
      *(short*)((char*)H1s + by1) = f2bf(z1);
    }
  __syncthreads();

  f32x4 acc2[4][2];
  #pragma unroll
  for (int mf = 0; mf < 4; ++mf) { f32x4 z = {0.f,0.f,0.f,0.f}; acc2[mf][0] = z; acc2[mf][1] = z; }
  #pragma unroll
  for (int ks = 0; ks < 4; ++ks) {
    svec8 bw0 = *(const svec8*)(w2p + (((ks * 8 + nfb + 0) * 64 + lane) << 3));
    svec8 bw1 = *(const svec8*)(w2p + (((ks * 8 + nfb + 1) * 64 + lane) << 3));
    #pragma unroll
    for (int mf = 0; mf < 4; ++mf) {
      int row = mf * 16 + l16;
      int byt = (row * 256 + ks * 64 + g16 * 16) ^ ((row & 7) << 4);
      svec8 a = *(const svec8*)((const char*)H1s + byt);
      acc2[mf][0] = mfma16(a, bw0, acc2[mf][0]);
      acc2[mf][1] = mfma16(a, bw1, acc2[mf][1]);
    }
  }

  float bi20 = b2v[col0], bi21 = b2v[col1];
  float ga20 = g2v[col0], ga21 = g2v[col1];
  float bb20 = be2v[col0], bb21 = be2v[col1];
  float y2[4][2][4];
  #pragma unroll
  for (int mf = 0; mf < 4; ++mf)
    #pragma unroll
    for (int r = 0; r < 4; ++r) {
      float y0 = fmaxf(acc2[mf][0][r] + bi20, 0.f);
      float y1 = fmaxf(acc2[mf][1][r] + bi21, 0.f);
      y2[mf][0][r] = y0; y2[mf][1][r] = y1;
      ps[mf][r] = y0 + y1;
      pq[mf][r] = y0 * y0 + y1 * y1;
    }
  #pragma unroll
  for (int mk = 1; mk <= 8; mk <<= 1)
    #pragma unroll
    for (int mf = 0; mf < 4; ++mf)
      #pragma unroll
      for (int r = 0; r < 4; ++r) {
        ps[mf][r] += __shfl_xor(ps[mf][r], mk, 64);
        pq[mf][r] += __shfl_xor(pq[mf][r], mk, 64);
      }
  if (l16 == 0) {
    #pragma unroll
    for (int mf = 0; mf < 4; ++mf)
      #pragma unroll
      for (int r = 0; r < 4; ++r) {
        redA[wv][mf * 16 + g16 * 4 + r] = ps[mf][r];
        redB[wv][mf * 16 + g16 * 4 + r] = pq[mf][r];
      }
  }
  __syncthreads();
  #pragma unroll
  for (int mf = 0; mf < 4; ++mf)
    #pragma unroll
    for (int r = 0; r < 4; ++r) {
      int rr = mf * 16 + g16 * 4 + r;
      float s = redA[0][rr] + redA[1][rr] + redA[2][rr] + redA[3][rr];
      float q = redB[0][rr] + redB[1][rr] + redB[2][rr] + redB[3][rr];
      float mu = s * (1.f / 128.f);
      float var = fmaxf(q * (1.f / 128.f) - mu * mu, 0.f);
      float rstd = rsqrtf(var + LN_EPS);
      float z0 = (y2[mf][0][r] - mu) * rstd * ga20 + bb20;
      float z1 = (y2[mf][1][r] - mu) * rstd * ga21 + bb21;
      int by0 = (rr * 256 + col0 * 2) ^ ((rr & 7) << 4);
      int by1 = (rr * 256 + col1 * 2) ^ ((rr & 7) << 4);
      *(short*)((char*)Xs + by0) = f2bf(z0);
      *(short*)((char*)Xs + by1) = f2bf(z1);
    }
  __syncthreads();

  f32x4 acc3[4][2];
  #pragma unroll
  for (int mf = 0; mf < 4; ++mf) { f32x4 z = {0.f,0.f,0.f,0.f}; acc3[mf][0] = z; acc3[mf][1] = z; }
  #pragma unroll
  for (int ks = 0; ks < 4; ++ks) {
    svec8 bw0 = *(const svec8*)(w3p + (((ks * 8 + nfb + 0) * 64 + lane) << 3));
    svec8 bw1 = *(const svec8*)(w3p + (((ks * 8 + nfb + 1) * 64 + lane) << 3));
    #pragma unroll
    for (int mf = 0; mf < 4; ++mf) {
      int row = mf * 16 + l16;
      int byt = (row * 256 + ks * 64 + g16 * 16) ^ ((row & 7) << 4);
      svec8 a = *(const svec8*)((const char*)Xs + byt);
      acc3[mf][0] = mfma16(a, bw0, acc3[mf][0]);
      acc3[mf][1] = mfma16(a, bw1, acc3[mf][1]);
    }
  }
  float bi30 = b3v[col0], bi31 = b3v[col1];
  #pragma unroll
  for (int mf = 0; mf < 4; ++mf)
    #pragma unroll
    for (int r = 0; r < 4; ++r) {
      int rr = mf * 16 + g16 * 4 + r;
      int gr = r0 + rr;
      if (gr < N) {
        mhb[(size_t)gr * 128 + col0] = f2bf(acc3[mf][0][r] + bi30);
        mhb[(size_t)gr * 128 + col1] = f2bf(acc3[mf][1][r] + bi31);
      }
    }
}

// ---- relu(q+m) with packed f32; emits B-frags + sum/sumsq ----
__device__ __forceinline__ void relu_stats(const svec8* qv, const svec8* mv,
                                           svec8* yf, float& ps_o, float& pq_o) {
  f32x2 psv = {0.f, 0.f}, pqv = {0.f, 0.f};
  #pragma unroll
  for (int ks2 = 0; ks2 < 4; ++ks2) {
    uvec4 qu = __builtin_bit_cast(uvec4, qv[ks2]);
    uvec4 mu = __builtin_bit_cast(uvec4, mv[ks2]);
    uvec4 u;
    #pragma unroll
    for (int p = 0; p < 4; ++p) {
      f32x2 y = __builtin_elementwise_max(up2(qu[p]) + up2(mu[p]), (f32x2){0.f, 0.f});
      psv += y;
      pqv += y * y;
      u[p] = pk2(y[0], y[1]);
    }
    yf[ks2] = __builtin_bit_cast(svec8, u);
  }
  float ps = psv[0] + psv[1], pq = pqv[0] + pqv[1];
  ps += __shfl_xor(ps, 16, 64); pq += __shfl_xor(pq, 16, 64);
  ps += __shfl_xor(ps, 32, 64); pq += __shfl_xor(pq, 32, 64);
  ps_o = ps; pq_o = pq;
}

// ---- folded LN1 affine + bias + relu + folded LN2+layer3 + tanh, packed f32 ----
__device__ __forceinline__ void epilogue(const f32x4* acc2, float rstd1, float mu1,
    const float* s2v, const float* b2pv, const float* gwv, float Sgw, float cb,
    float* __restrict__ hout, int e, bool valid, int lane, int g) {
  f32x2 rst = {rstd1, rstd1};
  f32x2 nmu = {-rstd1 * mu1, -rstd1 * mu1};
  f32x2 psv = {0.f,0.f}, pqv = {0.f,0.f}, pwv = {0.f,0.f};
  #pragma unroll
  for (int nf = 0; nf < 8; ++nf) {
    f32x4 s2 = *(const f32x4*)(s2v  + nf * 16 + g * 4);
    f32x4 bb = *(const f32x4*)(b2pv + nf * 16 + g * 4);
    f32x4 gw = *(const f32x4*)(gwv  + nf * 16 + g * 4);
    #pragma unroll
    for (int p = 0; p < 2; ++p) {
      f32x2 a   = { acc2[nf][2*p], acc2[nf][2*p+1] };
      f32x2 s2p = { s2[2*p], s2[2*p+1] };
      f32x2 bbp = { bb[2*p], bb[2*p+1] };
      f32x2 gwp = { gw[2*p], gw[2*p+1] };
      f32x2 h = rst * a + (nmu * s2p + bbp);
      f32x2 y = __builtin_elementwise_max(h, (f32x2){0.f, 0.f});
      psv += y;
      pqv += y * y;
      pwv += y * gwp;
    }
  }
  float ps2 = psv[0] + psv[1], pq2 = pqv[0] + pqv[1], pw2 = pwv[0] + pwv[1];
  ps2 += __shfl_xor(ps2, 16, 64); pq2 += __shfl_xor(pq2, 16, 64); pw2 += __shfl_xor(pw2, 16, 64);
  ps2 += __shfl_xor(ps2, 32, 64); pq2 += __shfl_xor(pq2, 32, 64); pw2 += __shfl_xor(pw2, 32, 64);
  float mu2   = ps2 * (1.f / 128.f);
  float var2  = fmaxf(pq2 * (1.f / 128.f) - mu2 * mu2, 0.f);
  float rstd2 = rsqrtf(var2 + LN_EPS);
  float p3 = fmaf(rstd2, pw2 - mu2 * Sgw, cb);
  if (lane < 16 && valid) hout[e] = tanhf(p3);
}

// ---------------- edge MLP: EG=2 (32 edges/wave), W2' in LDS, XCD-swizzled blocks ---------
__global__ __launch_bounds__(256, 3) void edge_mlp_kernel(
    const short* __restrict__ qwt, const short* __restrict__ mwt,
    const int* __restrict__ rowi, const int* __restrict__ coli,
    const short* __restrict__ w2p,
    const float* __restrict__ s2v, const float* __restrict__ b2pv,
    const float* __restrict__ gwv, const float* __restrict__ consts,
    float* __restrict__ hout, int E)
{
  __shared__ short w2s[16384];   // 32 KB: all W2' fragments

  const int tid  = threadIdx.x;
  const int wv   = tid >> 6;
  const int lane = tid & 63;
  const int g    = lane >> 4;
  const int l16  = lane & 15;

  // bijective XCD-aware block swizzle (m204)
  const int nb  = gridDim.x;
  const int q8  = nb >> 3, r8 = nb & 7;
  const int xcd = blockIdx.x & 7, sub = blockIdx.x >> 3;
  const int bid = (xcd < r8 ? xcd * (q8 + 1) : r8 * (q8 + 1) + (xcd - r8) * q8) + sub;

  // stage W2' fragments (linear copy)
  #pragma unroll
  for (int it = 0; it < 8; ++it) {
    int o = (it * 256 + tid) * 8;    // shorts
    *(f32x4*)(w2s + o) = *(const f32x4*)(w2p + o);
  }
  __syncthreads();

  const int eb = bid * 128 + wv * 32;
  const int e0 = eb + l16, e1 = eb + 16 + l16;
  const bool v0 = (e0 < E), v1 = (e1 < E);
  const int ee0 = v0 ? e0 : 0, ee1 = v1 ? e1 : 0;
  const short* q0 = qwt + (size_t)rowi[ee0] * 128 + g * 8;
  const short* m0 = mwt + (size_t)coli[ee0] * 128 + g * 8;
  const short* q1 = qwt + (size_t)rowi[ee1] * 128 + g * 8;
  const short* m1 = mwt + (size_t)coli[ee1] * 128 + g * 8;

  // issue all 16 gathers up front
  svec8 qv0[4], mv0[4], qv1[4], mv1[4];
  #pragma unroll
  for (int ks2 = 0; ks2 < 4; ++ks2) {
    qv0[ks2] = *(const svec8*)(q0 + ks2 * 32);
    mv0[ks2] = *(const svec8*)(m0 + ks2 * 32);
    qv1[ks2] = *(const svec8*)(q1 + ks2 * 32);
    mv1[ks2] = *(const svec8*)(m1 + ks2 * 32);
  }

  svec8 yf0[4], yf1[4];
  float ps0, pq0, ps1, pq1;
  relu_stats(qv0, mv0, yf0, ps0, pq0);
  relu_stats(qv1, mv1, yf1, ps1, pq1);
  float mu1_0   = ps0 * (1.f / 128.f);
  float rstd1_0 = rsqrtf(fmaxf(pq0 * (1.f / 128.f) - mu1_0 * mu1_0, 0.f) + LN_EPS);
  float mu1_1   = ps1 * (1.f / 128.f);
  float rstd1_1 = rsqrtf(fmaxf(pq1 * (1.f / 128.f) - mu1_1 * mu1_1, 0.f) + LN_EPS);

  // layer 2 for both edge groups, sharing each W2' fragment read from LDS
  f32x4 acc2a[8], acc2b[8];
  #pragma unroll
  for (int nf = 0; nf < 8; ++nf) { f32x4 z = {0.f,0.f,0.f,0.f}; acc2a[nf] = z; acc2b[nf] = z; }
  __builtin_amdgcn_s_setprio(1);
  #pragma unroll
  for (int ks2 = 0; ks2 < 4; ++ks2) {
    #pragma unroll
    for (int nf = 0; nf < 8; ++nf) {
      svec8 w = *(const svec8*)(w2s + (((ks2 * 8 + nf) * 64 + lane) << 3));
      acc2a[nf] = mfma16(w, yf0[ks2], acc2a[nf]);
      acc2b[nf] = mfma16(w, yf1[ks2], acc2b[nf]);
    }
  }
  __builtin_amdgcn_s_setprio(0);

  float Sgw = consts[0], cb = consts[1];
  epilogue(acc2a, rstd1_0, mu1_0, s2v, b2pv, gwv, Sgw, cb, hout, e0, v0, lane, g);
  epilogue(acc2b, rstd1_1, mu1_1, s2v, b2pv, gwv, Sgw, cb, hout, e1, v1, lane, g);
}

// ---------------- segment sum: full wave per node, 8 edges in flight ----------------
__global__ __launch_bounds__(256) void segsum_kernel(
    const int* __restrict__ off, const int* __restrict__ coli,
    const float* __restrict__ hbuf, const short* __restrict__ mhb,
    float* __restrict__ out, int N)
{
  int wv = threadIdx.x >> 6, lane = threadIdx.x & 63;
  int i = blockIdx.x * 4 + wv;
  if (i >= N) return;
  // bounds are wave-uniform: pin them to SGPRs so h-loads become scalar loads
  int s = __builtin_amdgcn_readfirstlane(off[i]);
  int e = __builtin_amdgcn_readfirstlane(off[i + 1]);
  f32x2 acc = {0.f, 0.f};
  int k = s;
  for (; k + 8 <= e; k += 8) {
    float h[8]; unsigned w[8];
    #pragma unroll
    for (int u = 0; u < 8; ++u) {
      h[u] = hbuf[k + u];
      w[u] = *(const unsigned*)(mhb + (size_t)coli[k + u] * 128 + lane * 2);
    }
    #pragma unroll
    for (int u = 0; u < 8; ++u)
      acc += (f32x2){h[u], h[u]} * up2(w[u]);
  }
  for (; k < e; ++k) {
    float h = hbuf[k];
    unsigned w = *(const unsigned*)(mhb + (size_t)coli[k] * 128 + lane * 2);
    acc += (f32x2){h, h} * up2(w);
  }
  *(f32x2*)(out + (size_t)i * 128 + lane * 2) = acc;
}

extern "C" void kernel_launch(void* const* d_in, const int* in_sizes, int n_in,
                              void* d_out, int out_size, void* d_ws, size_t ws_size,
                              hipStream_t stream) {
  const float* query = (const float*)d_in[0];
  const float* mem   = (const float*)d_in[1];
  const int*   row   = (const int*)d_in[2];
  const int*   col   = (const int*)d_in[3];
  const float* pW1 = (const float*)d_in[4];  const float* pb1 = (const float*)d_in[5];
  const float* pW2 = (const float*)d_in[6];  const float* pb2 = (const float*)d_in[7];
  const float* pW3 = (const float*)d_in[8];  const float* pb3 = (const float*)d_in[9];
  const float* pg1 = (const float*)d_in[10]; const float* pbe1 = (const float*)d_in[11];
  const float* pg2 = (const float*)d_in[12]; const float* pbe2 = (const float*)d_in[13];
  const float* mW1 = (const float*)d_in[14]; const float* mb1 = (const float*)d_in[15];
  const float* mW2 = (const float*)d_in[16]; const float* mb2 = (const float*)d_in[17];
  const float* mW3 = (const float*)d_in[18]; const float* mb3 = (const float*)d_in[19];
  const float* mg1 = (const float*)d_in[20]; const float* mbe1 = (const float*)d_in[21];
  const float* mg2 = (const float*)d_in[22]; const float* mbe2 = (const float*)d_in[23];

  const int N = in_sizes[0] / 128;
  const int E = in_sizes[2];

  char* ws = (char*)d_ws;
  short* w1qp = (short*)(ws + 0);        // 32768 B
  short* w1mp = (short*)(ws + 32768);    // 32768 B
  short* w2p  = (short*)(ws + 65536);    // 32768 B (scaled by g1)
  short* mw1p = (short*)(ws + 98304);    // 32768 B
  short* mw2p = (short*)(ws + 131072);   // 32768 B
  short* mw3p = (short*)(ws + 163840);   // 32768 B
  float* s2v  = (float*)(ws + 196608);   // 512 B
  float* b2pv = (float*)(ws + 197120);   // 512 B
  float* gwv  = (float*)(ws + 197632);   // 512 B
  float* cons = (float*)(ws + 198144);   // 64 B
  int*   offs = (int*)(ws + 198208);     // (N+1)*4
  size_t o = 198208 + (((size_t)(N + 1) * 4 + 255) / 256) * 256;
  short* qwt  = (short*)(ws + o);  o += (size_t)N * 128 * 2;   // bf16 q@W1t + b1
  short* mwt  = (short*)(ws + o);  o += (size_t)N * 128 * 2;   // bf16 m@W1b
  short* mhb  = (short*)(ws + o);  o += (size_t)N * 128 * 2;   // bf16 mem_head
  float* hbuf = (float*)(ws + o);  o += (size_t)E * 4;

  if (ws_size < o) return;

  const int nboff = (N + 1 + 255) / 256;
  setup_kernel<<<384 + nboff + 1, 256, 0, stream>>>(
      pW1, pW2, pg1, mW1, mW2, mW3, w1qp, w1mp, w2p, mw1p, mw2p, mw3p,
      row, E, N, offs,
      pg1, pbe1, pb2, pg2, pW3, pbe2, pb3, s2v, b2pv, gwv, cons, nboff);

  const int nbm = (N + 63) / 64;
  node_kernel<<<2 * nbm, 256, 0, stream>>>(
      mem, query, mw1p, mw2p, mw3p, w1mp, w1qp,
      mb1, mb2, mb3, mg1, mbe1, mg2, mbe2, pb1,
      mhb, mwt, qwt, N, nbm);

  edge_mlp_kernel<<<(E + 127) / 128, 256, 0, stream>>>(
      qwt, mwt, row, col, w2p, s2v, b2pv, gwv, cons, hbuf, E);

  segsum_kernel<<<(N + 3) / 4, 256, 0, stream>>>(offs, col, hbuf, mhb, (float*)d_out, N);
}

// Round 12
// 171.687 us; speedup vs baseline: 2.3566x; 1.0427x over previous
//
#include <hip/hip_runtime.h>
#include <hip/hip_bf16.h>

typedef __attribute__((ext_vector_type(8))) short  svec8;
typedef __attribute__((ext_vector_type(4))) short  svec4;
typedef __attribute__((ext_vector_type(8))) __bf16 bfvec8;
typedef __attribute__((ext_vector_type(4))) float  f32x4;
typedef __attribute__((ext_vector_type(2))) float  f32x2;
typedef __attribute__((ext_vector_type(4))) unsigned uvec4;

#define LN_EPS 1e-3f

__device__ __forceinline__ short f2bf(float f) {
  union { float f; unsigned u; } v; v.f = f;
  unsigned u = v.u;
  u += 0x7fff + ((u >> 16) & 1);   // round-to-nearest-even
  return (short)(u >> 16);
}

__device__ __forceinline__ unsigned pk2(float a, float b) {
  unsigned short ua = __builtin_bit_cast(unsigned short, (__bf16)a);
  unsigned short ub = __builtin_bit_cast(unsigned short, (__bf16)b);
  return (unsigned)ua | ((unsigned)ub << 16);
}

__device__ __forceinline__ f32x2 up2(unsigned w) {   // u32 of 2 bf16 -> f32x2
  f32x2 r;
  r[0] = __builtin_bit_cast(float, w << 16);
  r[1] = __builtin_bit_cast(float, w & 0xffff0000u);
  return r;
}

__device__ __forceinline__ f32x4 mfma16(svec8 a, svec8 b, f32x4 c) {
  return __builtin_amdgcn_mfma_f32_16x16x32_bf16(
      __builtin_bit_cast(bfvec8, a), __builtin_bit_cast(bfvec8, b), c, 0, 0, 0);
}

// ================= setup: pack 6 weights + CSR offsets + folded constants, ONE launch ====
__global__ __launch_bounds__(256) void setup_kernel(
    const float* __restrict__ pW1, const float* __restrict__ pW2,
    const float* __restrict__ pg1,
    const float* __restrict__ mW1, const float* __restrict__ mW2,
    const float* __restrict__ mW3,
    short* __restrict__ w1qp, short* __restrict__ w1mp,
    short* __restrict__ w2p,  short* __restrict__ mw1p,
    short* __restrict__ mw2p, short* __restrict__ mw3p,
    const int* __restrict__ row, int E, int N, int* __restrict__ off,
    const float* __restrict__ g1, const float* __restrict__ be1,
    const float* __restrict__ b2, const float* __restrict__ g2,
    const float* __restrict__ w3, const float* __restrict__ be2,
    const float* __restrict__ b3,
    float* __restrict__ s2, float* __restrict__ b2pv,
    float* __restrict__ gw, float* __restrict__ consts, int nboff)
{
  const int b = blockIdx.x;
  const int tid = threadIdx.x;
  if (b < 384) {                       // ---- pack weights: 6 * 16384 elems ----
    int idx = b * 256 + tid;
    int which = idx >> 14, p = idx & 16383;
    int j = p & 7, lane = (p >> 3) & 63, t = p >> 9;
    int nf = t & 7, ks = t >> 3;
    int k = ks * 32 + (lane >> 4) * 8 + j;
    int n = nf * 16 + (lane & 15);
    const float* src; short* dst; float scale = 1.f;
    switch (which) {
      case 0:  src = pW1;         dst = w1qp; break;
      case 1:  src = pW1 + 16384; dst = w1mp; break;
      case 2:  src = pW2;         dst = w2p; scale = pg1[k]; break;
      case 3:  src = mW1;         dst = mw1p; break;
      case 4:  src = mW2;         dst = mw2p; break;
      default: src = mW3;         dst = mw3p; break;
    }
    dst[p] = f2bf(scale * src[k * 128 + n]);
  } else if (b < 384 + nboff) {        // ---- CSR offsets via binary search ----
    int i = (b - 384) * 256 + tid;
    if (i > N) return;
    int lo = 0, hi = E;
    while (lo < hi) { int mid = (lo + hi) >> 1; if (row[mid] < i) lo = mid + 1; else hi = mid; }
    off[i] = lo;
  } else {                             // ---- folded constants ----
    __shared__ float tmp[256];
    int n = tid;
    if (n < 128) {
      float s = 0.f, bb = 0.f;
      for (int k = 0; k < 128; ++k) {
        float w = pW2[k * 128 + n];
        s  = fmaf(g1[k],  w, s);
        bb = fmaf(be1[k], w, bb);
      }
      s2[n]   = s;
      b2pv[n] = bb + b2[n];
      float g = g2[n] * w3[n];
      gw[n] = g;
      tmp[n]       = g;
      tmp[128 + n] = be2[n] * w3[n];
    }
    __syncthreads();
    if (n == 0) {
      float a = 0.f, c = 0.f;
      for (int i = 0; i < 128; ++i) { a += tmp[i]; c += tmp[128 + i]; }
      consts[0] = a;
      consts[1] = c + b3[0];
    }
  }
}

// ======== node kernel v2: wave-autonomous — each wave owns 16 rows x all 128 cols ========
// blocks [0,nbm): mem MLP (+ fused mwt proj); [nbm,2nbm): query proj. ZERO barriers.
__global__ __launch_bounds__(256) void node_kernel(
    const float* __restrict__ mem, const float* __restrict__ query,
    const short* __restrict__ w1p, const short* __restrict__ w2p, const short* __restrict__ w3p,
    const short* __restrict__ wmp, const short* __restrict__ wqp,
    const float* __restrict__ b1v, const float* __restrict__ b2v, const float* __restrict__ b3v,
    const float* __restrict__ g1v, const float* __restrict__ be1v,
    const float* __restrict__ g2v, const float* __restrict__ be2v,
    const float* __restrict__ pb1,
    short* __restrict__ mhb, short* __restrict__ mwt, short* __restrict__ qwt,
    int N, int nbm)
{
  __shared__ char Hs[4][4096];   // wave-private 16x128 bf16 slices (swizzled)

  const int tid  = threadIdx.x;
  const int wv   = tid >> 6;
  const int lane = tid & 63;
  const int g    = lane >> 4;    // k-quarter / row-group
  const int l16  = lane & 15;
  const bool is_mem = (blockIdx.x < nbm);
  const int r0   = (is_mem ? blockIdx.x : blockIdx.x - nbm) * 64 + wv * 16;
  const float* src = is_mem ? mem : query;

  // ---- direct A-fragment load: row = l16, k = ks*32 + g*8 + j (no LDS, no barrier) ----
  int grow = r0 + l16; if (grow >= N) grow = N - 1;
  const float* xrow = src + (size_t)grow * 128 + g * 8;
  svec8 xf[4];
  #pragma unroll
  for (int ks = 0; ks < 4; ++ks) {
    f32x4 a = *(const f32x4*)(xrow + ks * 32);
    f32x4 b = *(const f32x4*)(xrow + ks * 32 + 4);
    uvec4 u;
    u[0] = pk2(a[0], a[1]); u[1] = pk2(a[2], a[3]);
    u[2] = pk2(b[0], b[1]); u[3] = pk2(b[2], b[3]);
    xf[ks] = __builtin_bit_cast(svec8, u);
  }

  if (!is_mem) {
    // ---- query projection: qwt = q @ W1_top + b1 ----
    f32x4 acc[8];
    #pragma unroll
    for (int nf = 0; nf < 8; ++nf) { f32x4 z = {0.f,0.f,0.f,0.f}; acc[nf] = z; }
    #pragma unroll
    for (int ks = 0; ks < 4; ++ks)
      #pragma unroll
      for (int nf = 0; nf < 8; ++nf) {
        svec8 bw = *(const svec8*)(wqp + (((ks * 8 + nf) * 64 + lane) << 3));
        acc[nf] = mfma16(xf[ks], bw, acc[nf]);
      }
    #pragma unroll
    for (int nf = 0; nf < 8; ++nf) {
      float bi = pb1[nf * 16 + l16];
      #pragma unroll
      for (int r = 0; r < 4; ++r) {
        int gr = r0 + g * 4 + r;
        if (gr < N) qwt[(size_t)gr * 128 + nf * 16 + l16] = f2bf(acc[nf][r] + bi);
      }
    }
    return;
  }

  // ---- mem path layer 1: mem-MLP W1 AND mwt projection, sharing xf ----
  f32x4 acc[8], accm[8];
  #pragma unroll
  for (int nf = 0; nf < 8; ++nf) { f32x4 z = {0.f,0.f,0.f,0.f}; acc[nf] = z; accm[nf] = z; }
  #pragma unroll
  for (int ks = 0; ks < 4; ++ks)
    #pragma unroll
    for (int nf = 0; nf < 8; ++nf) {
      svec8 bw = *(const svec8*)(w1p + (((ks * 8 + nf) * 64 + lane) << 3));
      svec8 bm = *(const svec8*)(wmp + (((ks * 8 + nf) * 64 + lane) << 3));
      acc[nf]  = mfma16(xf[ks], bw, acc[nf]);
      accm[nf] = mfma16(xf[ks], bm, accm[nf]);
    }
  #pragma unroll
  for (int nf = 0; nf < 8; ++nf)
    #pragma unroll
    for (int r = 0; r < 4; ++r) {
      int gr = r0 + g * 4 + r;
      if (gr < N) mwt[(size_t)gr * 128 + nf * 16 + l16] = f2bf(accm[nf][r]);
    }

  char* slice = Hs[wv];

  // ---- bias + relu + LN1 (4-shuffle reduce over l16) + z -> wave-private LDS ----
  float ps[4] = {0,0,0,0}, pq[4] = {0,0,0,0};
  #pragma unroll
  for (int nf = 0; nf < 8; ++nf) {
    float bi = b1v[nf * 16 + l16];
    #pragma unroll
    for (int r = 0; r < 4; ++r) {
      float y = fmaxf(acc[nf][r] + bi, 0.f);
      acc[nf][r] = y;
      ps[r] += y;
      pq[r] = fmaf(y, y, pq[r]);
    }
  }
  #pragma unroll
  for (int mk = 1; mk <= 8; mk <<= 1)
    #pragma unroll
    for (int r = 0; r < 4; ++r) {
      ps[r] += __shfl_xor(ps[r], mk, 64);
      pq[r] += __shfl_xor(pq[r], mk, 64);
    }
  #pragma unroll
  for (int r = 0; r < 4; ++r) {
    float mu = ps[r] * (1.f / 128.f);
    float var = fmaxf(pq[r] * (1.f / 128.f) - mu * mu, 0.f);
    float rstd = rsqrtf(var + LN_EPS);
    int rloc = g * 4 + r;
    #pragma unroll
    for (int nf = 0; nf < 8; ++nf) {
      float ga = g1v[nf * 16 + l16], bb = be1v[nf * 16 + l16];
      float z = (acc[nf][r] - mu) * rstd * ga + bb;
      int byt = (rloc * 256 + (nf * 16 + l16) * 2) ^ ((rloc & 7) << 4);
      *(short*)(slice + byt) = f2bf(z);
    }
  }

  // ---- layer 2: A-frags from wave-private LDS, B = w2p ----
  svec8 hf[4];
  #pragma unroll
  for (int ks = 0; ks < 4; ++ks) {
    int byt = (l16 * 256 + (ks * 32 + g * 8) * 2) ^ ((l16 & 7) << 4);
    hf[ks] = *(const svec8*)(slice + byt);
  }
  f32x4 acc2[8];
  #pragma unroll
  for (int nf = 0; nf < 8; ++nf) { f32x4 z = {0.f,0.f,0.f,0.f}; acc2[nf] = z; }
  #pragma unroll
  for (int ks = 0; ks < 4; ++ks)
    #pragma unroll
    for (int nf = 0; nf < 8; ++nf) {
      svec8 bw = *(const svec8*)(w2p + (((ks * 8 + nf) * 64 + lane) << 3));
      acc2[nf] = mfma16(hf[ks], bw, acc2[nf]);
    }

  // ---- bias + relu + LN2 + z2 -> LDS (reuse slice) ----
  #pragma unroll
  for (int r = 0; r < 4; ++r) { ps[r] = 0.f; pq[r] = 0.f; }
  #pragma unroll
  for (int nf = 0; nf < 8; ++nf) {
    float bi = b2v[nf * 16 + l16];
    #pragma unroll
    for (int r = 0; r < 4; ++r) {
      float y = fmaxf(acc2[nf][r] + bi, 0.f);
      acc2[nf][r] = y;
      ps[r] += y;
      pq[r] = fmaf(y, y, pq[r]);
    }
  }
  #pragma unroll
  for (int mk = 1; mk <= 8; mk <<= 1)
    #pragma unroll
    for (int r = 0; r < 4; ++r) {
      ps[r] += __shfl_xor(ps[r], mk, 64);
      pq[r] += __shfl_xor(pq[r], mk, 64);
    }
  #pragma unroll
  for (int r = 0; r < 4; ++r) {
    float mu = ps[r] * (1.f / 128.f);
    float var = fmaxf(pq[r] * (1.f / 128.f) - mu * mu, 0.f);
    float rstd = rsqrtf(var + LN_EPS);
    int rloc = g * 4 + r;
    #pragma unroll
    for (int nf = 0; nf < 8; ++nf) {
      float ga = g2v[nf * 16 + l16], bb = be2v[nf * 16 + l16];
      float z = (acc2[nf][r] - mu) * rstd * ga + bb;
      int byt = (rloc * 256 + (nf * 16 + l16) * 2) ^ ((rloc & 7) << 4);
      *(short*)(slice + byt) = f2bf(z);
    }
  }

  // ---- layer 3: A-frags from LDS, B = w3p; write mhb ----
  #pragma unroll
  for (int ks = 0; ks < 4; ++ks) {
    int byt = (l16 * 256 + (ks * 32 + g * 8) * 2) ^ ((l16 & 7) << 4);
    hf[ks] = *(const svec8*)(slice + byt);
  }
  f32x4 acc3[8];
  #pragma unroll
  for (int nf = 0; nf < 8; ++nf) { f32x4 z = {0.f,0.f,0.f,0.f}; acc3[nf] = z; }
  #pragma unroll
  for (int ks = 0; ks < 4; ++ks)
    #pragma unroll
    for (int nf = 0; nf < 8; ++nf) {
      svec8 bw = *(const svec8*)(w3p + (((ks * 8 + nf) * 64 + lane) << 3));
      acc3[nf] = mfma16(hf[ks], bw, acc3[nf]);
    }
  #pragma unroll
  for (int nf = 0; nf < 8; ++nf) {
    float bi = b3v[nf * 16 + l16];
    #pragma unroll
    for (int r = 0; r < 4; ++r) {
      int gr = r0 + g * 4 + r;
      if (gr < N) mhb[(size_t)gr * 128 + nf * 16 + l16] = f2bf(acc3[nf][r] + bi);
    }
  }
}

// ---- relu(q+m) with packed f32; emits B-frags + sum/sumsq ----
__device__ __forceinline__ void relu_stats(const svec8* qv, const svec8* mv,
                                           svec8* yf, float& ps_o, float& pq_o) {
  f32x2 psv = {0.f, 0.f}, pqv = {0.f, 0.f};
  #pragma unroll
  for (int ks2 = 0; ks2 < 4; ++ks2) {
    uvec4 qu = __builtin_bit_cast(uvec4, qv[ks2]);
    uvec4 mu = __builtin_bit_cast(uvec4, mv[ks2]);
    uvec4 u;
    #pragma unroll
    for (int p = 0; p < 4; ++p) {
      f32x2 y = __builtin_elementwise_max(up2(qu[p]) + up2(mu[p]), (f32x2){0.f, 0.f});
      psv += y;
      pqv += y * y;
      u[p] = pk2(y[0], y[1]);
    }
    yf[ks2] = __builtin_bit_cast(svec8, u);
  }
  float ps = psv[0] + psv[1], pq = pqv[0] + pqv[1];
  ps += __shfl_xor(ps, 16, 64); pq += __shfl_xor(pq, 16, 64);
  ps += __shfl_xor(ps, 32, 64); pq += __shfl_xor(pq, 32, 64);
  ps_o = ps; pq_o = pq;
}

// ---- folded LN1 affine + bias + relu + folded LN2+layer3 + tanh, packed f32 ----
__device__ __forceinline__ void epilogue(const f32x4* acc2, float rstd1, float mu1,
    const float* s2v, const float* b2pv, const float* gwv, float Sgw, float cb,
    float* __restrict__ hout, int e, bool valid, int lane, int g) {
  f32x2 rst = {rstd1, rstd1};
  f32x2 nmu = {-rstd1 * mu1, -rstd1 * mu1};
  f32x2 psv = {0.f,0.f}, pqv = {0.f,0.f}, pwv = {0.f,0.f};
  #pragma unroll
  for (int nf = 0; nf < 8; ++nf) {
    f32x4 s2 = *(const f32x4*)(s2v  + nf * 16 + g * 4);
    f32x4 bb = *(const f32x4*)(b2pv + nf * 16 + g * 4);
    f32x4 gw = *(const f32x4*)(gwv  + nf * 16 + g * 4);
    #pragma unroll
    for (int p = 0; p < 2; ++p) {
      f32x2 a   = { acc2[nf][2*p], acc2[nf][2*p+1] };
      f32x2 s2p = { s2[2*p], s2[2*p+1] };
      f32x2 bbp = { bb[2*p], bb[2*p+1] };
      f32x2 gwp = { gw[2*p], gw[2*p+1] };
      f32x2 h = rst * a + (nmu * s2p + bbp);
      f32x2 y = __builtin_elementwise_max(h, (f32x2){0.f, 0.f});
      psv += y;
      pqv += y * y;
      pwv += y * gwp;
    }
  }
  float ps2 = psv[0] + psv[1], pq2 = pqv[0] + pqv[1], pw2 = pwv[0] + pwv[1];
  ps2 += __shfl_xor(ps2, 16, 64); pq2 += __shfl_xor(pq2, 16, 64); pw2 += __shfl_xor(pw2, 16, 64);
  ps2 += __shfl_xor(ps2, 32, 64); pq2 += __shfl_xor(pq2, 32, 64); pw2 += __shfl_xor(pw2, 32, 64);
  float mu2   = ps2 * (1.f / 128.f);
  float var2  = fmaxf(pq2 * (1.f / 128.f) - mu2 * mu2, 0.f);
  float rstd2 = rsqrtf(var2 + LN_EPS);
  float p3 = fmaf(rstd2, pw2 - mu2 * Sgw, cb);
  if (lane < 16 && valid) hout[e] = tanhf(p3);
}

// ---------------- edge MLP: EG=2 (32 edges/wave), W2' in LDS, XCD-swizzled blocks ---------
__global__ __launch_bounds__(256, 3) void edge_mlp_kernel(
    const short* __restrict__ qwt, const short* __restrict__ mwt,
    const int* __restrict__ rowi, const int* __restrict__ coli,
    const short* __restrict__ w2p,
    const float* __restrict__ s2v, const float* __restrict__ b2pv,
    const float* __restrict__ gwv, const float* __restrict__ consts,
    float* __restrict__ hout, int E)
{
  __shared__ short w2s[16384];   // 32 KB: all W2' fragments

  const int tid  = threadIdx.x;
  const int wv   = tid >> 6;
  const int lane = tid & 63;
  const int g    = lane >> 4;
  const int l16  = lane & 15;

  // bijective XCD-aware block swizzle (m204)
  const int nb  = gridDim.x;
  const int q8  = nb >> 3, r8 = nb & 7;
  const int xcd = blockIdx.x & 7, sub = blockIdx.x >> 3;
  const int bid = (xcd < r8 ? xcd * (q8 + 1) : r8 * (q8 + 1) + (xcd - r8) * q8) + sub;

  // stage W2' fragments (linear copy)
  #pragma unroll
  for (int it = 0; it < 8; ++it) {
    int o = (it * 256 + tid) * 8;    // shorts
    *(f32x4*)(w2s + o) = *(const f32x4*)(w2p + o);
  }
  __syncthreads();

  const int eb = bid * 128 + wv * 32;
  const int e0 = eb + l16, e1 = eb + 16 + l16;
  const bool v0 = (e0 < E), v1 = (e1 < E);
  const int ee0 = v0 ? e0 : 0, ee1 = v1 ? e1 : 0;
  const short* q0 = qwt + (size_t)rowi[ee0] * 128 + g * 8;
  const short* m0 = mwt + (size_t)coli[ee0] * 128 + g * 8;
  const short* q1 = qwt + (size_t)rowi[ee1] * 128 + g * 8;
  const short* m1 = mwt + (size_t)coli[ee1] * 128 + g * 8;

  // issue all 16 gathers up front
  svec8 qv0[4], mv0[4], qv1[4], mv1[4];
  #pragma unroll
  for (int ks2 = 0; ks2 < 4; ++ks2) {
    qv0[ks2] = *(const svec8*)(q0 + ks2 * 32);
    mv0[ks2] = *(const svec8*)(m0 + ks2 * 32);
    qv1[ks2] = *(const svec8*)(q1 + ks2 * 32);
    mv1[ks2] = *(const svec8*)(m1 + ks2 * 32);
  }

  svec8 yf0[4], yf1[4];
  float ps0, pq0, ps1, pq1;
  relu_stats(qv0, mv0, yf0, ps0, pq0);
  relu_stats(qv1, mv1, yf1, ps1, pq1);
  float mu1_0   = ps0 * (1.f / 128.f);
  float rstd1_0 = rsqrtf(fmaxf(pq0 * (1.f / 128.f) - mu1_0 * mu1_0, 0.f) + LN_EPS);
  float mu1_1   = ps1 * (1.f / 128.f);
  float rstd1_1 = rsqrtf(fmaxf(pq1 * (1.f / 128.f) - mu1_1 * mu1_1, 0.f) + LN_EPS);

  // layer 2 for both edge groups, sharing each W2' fragment read from LDS
  f32x4 acc2a[8], acc2b[8];
  #pragma unroll
  for (int nf = 0; nf < 8; ++nf) { f32x4 z = {0.f,0.f,0.f,0.f}; acc2a[nf] = z; acc2b[nf] = z; }
  __builtin_amdgcn_s_setprio(1);
  #pragma unroll
  for (int ks2 = 0; ks2 < 4; ++ks2) {
    #pragma unroll
    for (int nf = 0; nf < 8; ++nf) {
      svec8 w = *(const svec8*)(w2s + (((ks2 * 8 + nf) * 64 + lane) << 3));
      acc2a[nf] = mfma16(w, yf0[ks2], acc2a[nf]);
      acc2b[nf] = mfma16(w, yf1[ks2], acc2b[nf]);
    }
  }
  __builtin_amdgcn_s_setprio(0);

  float Sgw = consts[0], cb = consts[1];
  epilogue(acc2a, rstd1_0, mu1_0, s2v, b2pv, gwv, Sgw, cb, hout, e0, v0, lane, g);
  epilogue(acc2b, rstd1_1, mu1_1, s2v, b2pv, gwv, Sgw, cb, hout, e1, v1, lane, g);
}

// ---------------- segment sum: full wave per node, 8 edges in flight ----------------
__global__ __launch_bounds__(256) void segsum_kernel(
    const int* __restrict__ off, const int* __restrict__ coli,
    const float* __restrict__ hbuf, const short* __restrict__ mhb,
    float* __restrict__ out, int N)
{
  int wv = threadIdx.x >> 6, lane = threadIdx.x & 63;
  int i = blockIdx.x * 4 + wv;
  if (i >= N) return;
  int s = __builtin_amdgcn_readfirstlane(off[i]);
  int e = __builtin_amdgcn_readfirstlane(off[i + 1]);
  f32x2 acc = {0.f, 0.f};
  int k = s;
  for (; k + 8 <= e; k += 8) {
    float h[8]; unsigned w[8];
    #pragma unroll
    for (int u = 0; u < 8; ++u) {
      h[u] = hbuf[k + u];
      w[u] = *(const unsigned*)(mhb + (size_t)coli[k + u] * 128 + lane * 2);
    }
    #pragma unroll
    for (int u = 0; u < 8; ++u)
      acc += (f32x2){h[u], h[u]} * up2(w[u]);
  }
  for (; k < e; ++k) {
    float h = hbuf[k];
    unsigned w = *(const unsigned*)(mhb + (size_t)coli[k] * 128 + lane * 2);
    acc += (f32x2){h, h} * up2(w);
  }
  *(f32x2*)(out + (size_t)i * 128 + lane * 2) = acc;
}

extern "C" void kernel_launch(void* const* d_in, const int* in_sizes, int n_in,
                              void* d_out, int out_size, void* d_ws, size_t ws_size,
                              hipStream_t stream) {
  const float* query = (const float*)d_in[0];
  const float* mem   = (const float*)d_in[1];
  const int*   row   = (const int*)d_in[2];
  const int*   col   = (const int*)d_in[3];
  const float* pW1 = (const float*)d_in[4];  const float* pb1 = (const float*)d_in[5];
  const float* pW2 = (const float*)d_in[6];  const float* pb2 = (const float*)d_in[7];
  const float* pW3 = (const float*)d_in[8];  const float* pb3 = (const float*)d_in[9];
  const float* pg1 = (const float*)d_in[10]; const float* pbe1 = (const float*)d_in[11];
  const float* pg2 = (const float*)d_in[12]; const float* pbe2 = (const float*)d_in[13];
  const float* mW1 = (const float*)d_in[14]; const float* mb1 = (const float*)d_in[15];
  const float* mW2 = (const float*)d_in[16]; const float* mb2 = (const float*)d_in[17];
  const float* mW3 = (const float*)d_in[18]; const float* mb3 = (const float*)d_in[19];
  const float* mg1 = (const float*)d_in[20]; const float* mbe1 = (const float*)d_in[21];
  const float* mg2 = (const float*)d_in[22]; const float* mbe2 = (const float*)d_in[23];

  const int N = in_sizes[0] / 128;
  const int E = in_sizes[2];

  char* ws = (char*)d_ws;
  short* w1qp = (short*)(ws + 0);        // 32768 B
  short* w1mp = (short*)(ws + 32768);    // 32768 B
  short* w2p  = (short*)(ws + 65536);    // 32768 B (scaled by g1)
  short* mw1p = (short*)(ws + 98304);    // 32768 B
  short* mw2p = (short*)(ws + 131072);   // 32768 B
  short* mw3p = (short*)(ws + 163840);   // 32768 B
  float* s2v  = (float*)(ws + 196608);   // 512 B
  float* b2pv = (float*)(ws + 197120);   // 512 B
  float* gwv  = (float*)(ws + 197632);   // 512 B
  float* cons = (float*)(ws + 198144);   // 64 B
  int*   offs = (int*)(ws + 198208);     // (N+1)*4
  size_t o = 198208 + (((size_t)(N + 1) * 4 + 255) / 256) * 256;
  short* qwt  = (short*)(ws + o);  o += (size_t)N * 128 * 2;   // bf16 q@W1t + b1
  short* mwt  = (short*)(ws + o);  o += (size_t)N * 128 * 2;   // bf16 m@W1b
  short* mhb  = (short*)(ws + o);  o += (size_t)N * 128 * 2;   // bf16 mem_head
  float* hbuf = (float*)(ws + o);  o += (size_t)E * 4;

  if (ws_size < o) return;

  const int nboff = (N + 1 + 255) / 256;
  setup_kernel<<<384 + nboff + 1, 256, 0, stream>>>(
      pW1, pW2, pg1, mW1, mW2, mW3, w1qp, w1mp, w2p, mw1p, mw2p, mw3p,
      row, E, N, offs,
      pg1, pbe1, pb2, pg2, pW3, pbe2, pb3, s2v, b2pv, gwv, cons, nboff);

  const int nbm = (N + 63) / 64;
  node_kernel<<<2 * nbm, 256, 0, stream>>>(
      mem, query, mw1p, mw2p, mw3p, w1mp, w1qp,
      mb1, mb2, mb3, mg1, mbe1, mg2, mbe2, pb1,
      mhb, mwt, qwt, N, nbm);

  edge_mlp_kernel<<<(E + 127) / 128, 256, 0, stream>>>(
      qwt, mwt, row, col, w2p, s2v, b2pv, gwv, cons, hbuf, E);

  segsum_kernel<<<(N + 3) / 4, 256, 0, stream>>>(offs, col, hbuf, mhb, (float*)d_out, N);
}

// Round 13
// 165.321 us; speedup vs baseline: 2.4473x; 1.0385x over previous
//
#include <hip/hip_runtime.h>
#include <hip/hip_bf16.h>

typedef __attribute__((ext_vector_type(8))) short  svec8;
typedef __attribute__((ext_vector_type(4))) short  svec4;
typedef __attribute__((ext_vector_type(8))) __bf16 bfvec8;
typedef __attribute__((ext_vector_type(4))) float  f32x4;
typedef __attribute__((ext_vector_type(2))) float  f32x2;
typedef __attribute__((ext_vector_type(4))) unsigned uvec4;

#define LN_EPS 1e-3f

__device__ __forceinline__ short f2bf(float f) {
  union { float f; unsigned u; } v; v.f = f;
  unsigned u = v.u;
  u += 0x7fff + ((u >> 16) & 1);   // round-to-nearest-even
  return (short)(u >> 16);
}

__device__ __forceinline__ unsigned pk2(float a, float b) {
  unsigned short ua = __builtin_bit_cast(unsigned short, (__bf16)a);
  unsigned short ub = __builtin_bit_cast(unsigned short, (__bf16)b);
  return (unsigned)ua | ((unsigned)ub << 16);
}

__device__ __forceinline__ f32x2 up2(unsigned w) {   // u32 of 2 bf16 -> f32x2
  f32x2 r;
  r[0] = __builtin_bit_cast(float, w << 16);
  r[1] = __builtin_bit_cast(float, w & 0xffff0000u);
  return r;
}

__device__ __forceinline__ f32x4 mfma16(svec8 a, svec8 b, f32x4 c) {
  return __builtin_amdgcn_mfma_f32_16x16x32_bf16(
      __builtin_bit_cast(bfvec8, a), __builtin_bit_cast(bfvec8, b), c, 0, 0, 0);
}

// ================= setup: pack 6 weights + CSR offsets + folded constants, ONE launch ====
__global__ __launch_bounds__(256) void setup_kernel(
    const float* __restrict__ pW1, const float* __restrict__ pW2,
    const float* __restrict__ pg1,
    const float* __restrict__ mW1, const float* __restrict__ mW2,
    const float* __restrict__ mW3,
    short* __restrict__ w1qp, short* __restrict__ w1mp,
    short* __restrict__ w2p,  short* __restrict__ mw1p,
    short* __restrict__ mw2p, short* __restrict__ mw3p,
    const int* __restrict__ row, int E, int N, int* __restrict__ off,
    const float* __restrict__ g1, const float* __restrict__ be1,
    const float* __restrict__ b2, const float* __restrict__ g2,
    const float* __restrict__ w3, const float* __restrict__ be2,
    const float* __restrict__ b3,
    float* __restrict__ s2, float* __restrict__ b2pv,
    float* __restrict__ gw, float* __restrict__ consts, int nboff)
{
  const int b = blockIdx.x;
  const int tid = threadIdx.x;
  if (b < 384) {                       // ---- pack weights: 6 * 16384 elems ----
    int idx = b * 256 + tid;
    int which = idx >> 14, p = idx & 16383;
    int j = p & 7, lane = (p >> 3) & 63, t = p >> 9;
    int nf = t & 7, ks = t >> 3;
    int k = ks * 32 + (lane >> 4) * 8 + j;
    int n = nf * 16 + (lane & 15);
    const float* src; short* dst; float scale = 1.f;
    switch (which) {
      case 0:  src = pW1;         dst = w1qp; break;
      case 1:  src = pW1 + 16384; dst = w1mp; break;
      case 2:  src = pW2;         dst = w2p; scale = pg1[k]; break;
      case 3:  src = mW1;         dst = mw1p; break;
      case 4:  src = mW2;         dst = mw2p; break;
      default: src = mW3;         dst = mw3p; break;
    }
    dst[p] = f2bf(scale * src[k * 128 + n]);
  } else if (b < 384 + nboff) {        // ---- CSR offsets via binary search ----
    int i = (b - 384) * 256 + tid;
    if (i > N) return;
    int lo = 0, hi = E;
    while (lo < hi) { int mid = (lo + hi) >> 1; if (row[mid] < i) lo = mid + 1; else hi = mid; }
    off[i] = lo;
  } else {                             // ---- folded constants ----
    __shared__ float tmp[256];
    int n = tid;
    if (n < 128) {
      float s = 0.f, bb = 0.f;
      for (int k = 0; k < 128; ++k) {
        float w = pW2[k * 128 + n];
        s  = fmaf(g1[k],  w, s);
        bb = fmaf(be1[k], w, bb);
      }
      s2[n]   = s;
      b2pv[n] = bb + b2[n];
      float g = g2[n] * w3[n];
      gw[n] = g;
      tmp[n]       = g;
      tmp[128 + n] = be2[n] * w3[n];
    }
    __syncthreads();
    if (n == 0) {
      float a = 0.f, c = 0.f;
      for (int i = 0; i < 128; ++i) { a += tmp[i]; c += tmp[128 + i]; }
      consts[0] = a;
      consts[1] = c + b3[0];
    }
  }
}

// ======== node kernel v2: wave-autonomous — each wave owns 16 rows x all 128 cols ========
__global__ __launch_bounds__(256) void node_kernel(
    const float* __restrict__ mem, const float* __restrict__ query,
    const short* __restrict__ w1p, const short* __restrict__ w2p, const short* __restrict__ w3p,
    const short* __restrict__ wmp, const short* __restrict__ wqp,
    const float* __restrict__ b1v, const float* __restrict__ b2v, const float* __restrict__ b3v,
    const float* __restrict__ g1v, const float* __restrict__ be1v,
    const float* __restrict__ g2v, const float* __restrict__ be2v,
    const float* __restrict__ pb1,
    short* __restrict__ mhb, short* __restrict__ mwt, short* __restrict__ qwt,
    int N, int nbm)
{
  __shared__ char Hs[4][4096];   // wave-private 16x128 bf16 slices (swizzled)

  const int tid  = threadIdx.x;
  const int wv   = tid >> 6;
  const int lane = tid & 63;
  const int g    = lane >> 4;
  const int l16  = lane & 15;
  const bool is_mem = (blockIdx.x < nbm);
  const int r0   = (is_mem ? blockIdx.x : blockIdx.x - nbm) * 64 + wv * 16;
  const float* src = is_mem ? mem : query;

  int grow = r0 + l16; if (grow >= N) grow = N - 1;
  const float* xrow = src + (size_t)grow * 128 + g * 8;
  svec8 xf[4];
  #pragma unroll
  for (int ks = 0; ks < 4; ++ks) {
    f32x4 a = *(const f32x4*)(xrow + ks * 32);
    f32x4 b = *(const f32x4*)(xrow + ks * 32 + 4);
    uvec4 u;
    u[0] = pk2(a[0], a[1]); u[1] = pk2(a[2], a[3]);
    u[2] = pk2(b[0], b[1]); u[3] = pk2(b[2], b[3]);
    xf[ks] = __builtin_bit_cast(svec8, u);
  }

  if (!is_mem) {
    f32x4 acc[8];
    #pragma unroll
    for (int nf = 0; nf < 8; ++nf) { f32x4 z = {0.f,0.f,0.f,0.f}; acc[nf] = z; }
    #pragma unroll
    for (int ks = 0; ks < 4; ++ks)
      #pragma unroll
      for (int nf = 0; nf < 8; ++nf) {
        svec8 bw = *(const svec8*)(wqp + (((ks * 8 + nf) * 64 + lane) << 3));
        acc[nf] = mfma16(xf[ks], bw, acc[nf]);
      }
    #pragma unroll
    for (int nf = 0; nf < 8; ++nf) {
      float bi = pb1[nf * 16 + l16];
      #pragma unroll
      for (int r = 0; r < 4; ++r) {
        int gr = r0 + g * 4 + r;
        if (gr < N) qwt[(size_t)gr * 128 + nf * 16 + l16] = f2bf(acc[nf][r] + bi);
      }
    }
    return;
  }

  f32x4 acc[8], accm[8];
  #pragma unroll
  for (int nf = 0; nf < 8; ++nf) { f32x4 z = {0.f,0.f,0.f,0.f}; acc[nf] = z; accm[nf] = z; }
  #pragma unroll
  for (int ks = 0; ks < 4; ++ks)
    #pragma unroll
    for (int nf = 0; nf < 8; ++nf) {
      svec8 bw = *(const svec8*)(w1p + (((ks * 8 + nf) * 64 + lane) << 3));
      svec8 bm = *(const svec8*)(wmp + (((ks * 8 + nf) * 64 + lane) << 3));
      acc[nf]  = mfma16(xf[ks], bw, acc[nf]);
      accm[nf] = mfma16(xf[ks], bm, accm[nf]);
    }
  #pragma unroll
  for (int nf = 0; nf < 8; ++nf)
    #pragma unroll
    for (int r = 0; r < 4; ++r) {
      int gr = r0 + g * 4 + r;
      if (gr < N) mwt[(size_t)gr * 128 + nf * 16 + l16] = f2bf(accm[nf][r]);
    }

  char* slice = Hs[wv];

  float ps[4] = {0,0,0,0}, pq[4] = {0,0,0,0};
  #pragma unroll
  for (int nf = 0; nf < 8; ++nf) {
    float bi = b1v[nf * 16 + l16];
    #pragma unroll
    for (int r = 0; r < 4; ++r) {
      float y = fmaxf(acc[nf][r] + bi, 0.f);
      acc[nf][r] = y;
      ps[r] += y;
      pq[r] = fmaf(y, y, pq[r]);
    }
  }
  #pragma unroll
  for (int mk = 1; mk <= 8; mk <<= 1)
    #pragma unroll
    for (int r = 0; r < 4; ++r) {
      ps[r] += __shfl_xor(ps[r], mk, 64);
      pq[r] += __shfl_xor(pq[r], mk, 64);
    }
  #pragma unroll
  for (int r = 0; r < 4; ++r) {
    float mu = ps[r] * (1.f / 128.f);
    float var = fmaxf(pq[r] * (1.f / 128.f) - mu * mu, 0.f);
    float rstd = rsqrtf(var + LN_EPS);
    int rloc = g * 4 + r;
    #pragma unroll
    for (int nf = 0; nf < 8; ++nf) {
      float ga = g1v[nf * 16 + l16], bb = be1v[nf * 16 + l16];
      float z = (acc[nf][r] - mu) * rstd * ga + bb;
      int byt = (rloc * 256 + (nf * 16 + l16) * 2) ^ ((rloc & 7) << 4);
      *(short*)(slice + byt) = f2bf(z);
    }
  }

  svec8 hf[4];
  #pragma unroll
  for (int ks = 0; ks < 4; ++ks) {
    int byt = (l16 * 256 + (ks * 32 + g * 8) * 2) ^ ((l16 & 7) << 4);
    hf[ks] = *(const svec8*)(slice + byt);
  }
  f32x4 acc2[8];
  #pragma unroll
  for (int nf = 0; nf < 8; ++nf) { f32x4 z = {0.f,0.f,0.f,0.f}; acc2[nf] = z; }
  #pragma unroll
  for (int ks = 0; ks < 4; ++ks)
    #pragma unroll
    for (int nf = 0; nf < 8; ++nf) {
      svec8 bw = *(const svec8*)(w2p + (((ks * 8 + nf) * 64 + lane) << 3));
      acc2[nf] = mfma16(hf[ks], bw, acc2[nf]);
    }

  #pragma unroll
  for (int r = 0; r < 4; ++r) { ps[r] = 0.f; pq[r] = 0.f; }
  #pragma unroll
  for (int nf = 0; nf < 8; ++nf) {
    float bi = b2v[nf * 16 + l16];
    #pragma unroll
    for (int r = 0; r < 4; ++r) {
      float y = fmaxf(acc2[nf][r] + bi, 0.f);
      acc2[nf][r] = y;
      ps[r] += y;
      pq[r] = fmaf(y, y, pq[r]);
    }
  }
  #pragma unroll
  for (int mk = 1; mk <= 8; mk <<= 1)
    #pragma unroll
    for (int r = 0; r < 4; ++r) {
      ps[r] += __shfl_xor(ps[r], mk, 64);
      pq[r] += __shfl_xor(pq[r], mk, 64);
    }
  #pragma unroll
  for (int r = 0; r < 4; ++r) {
    float mu = ps[r] * (1.f / 128.f);
    float var = fmaxf(pq[r] * (1.f / 128.f) - mu * mu, 0.f);
    float rstd = rsqrtf(var + LN_EPS);
    int rloc = g * 4 + r;
    #pragma unroll
    for (int nf = 0; nf < 8; ++nf) {
      float ga = g2v[nf * 16 + l16], bb = be2v[nf * 16 + l16];
      float z = (acc2[nf][r] - mu) * rstd * ga + bb;
      int byt = (rloc * 256 + (nf * 16 + l16) * 2) ^ ((rloc & 7) << 4);
      *(short*)(slice + byt) = f2bf(z);
    }
  }

  #pragma unroll
  for (int ks = 0; ks < 4; ++ks) {
    int byt = (l16 * 256 + (ks * 32 + g * 8) * 2) ^ ((l16 & 7) << 4);
    hf[ks] = *(const svec8*)(slice + byt);
  }
  f32x4 acc3[8];
  #pragma unroll
  for (int nf = 0; nf < 8; ++nf) { f32x4 z = {0.f,0.f,0.f,0.f}; acc3[nf] = z; }
  #pragma unroll
  for (int ks = 0; ks < 4; ++ks)
    #pragma unroll
    for (int nf = 0; nf < 8; ++nf) {
      svec8 bw = *(const svec8*)(w3p + (((ks * 8 + nf) * 64 + lane) << 3));
      acc3[nf] = mfma16(hf[ks], bw, acc3[nf]);
    }
  #pragma unroll
  for (int nf = 0; nf < 8; ++nf) {
    float bi = b3v[nf * 16 + l16];
    #pragma unroll
    for (int r = 0; r < 4; ++r) {
      int gr = r0 + g * 4 + r;
      if (gr < N) mhb[(size_t)gr * 128 + nf * 16 + l16] = f2bf(acc3[nf][r] + bi);
    }
  }
}

// ---- relu(q+m) with packed f32; emits B-frags + sum/sumsq ----
__device__ __forceinline__ void relu_stats(const svec8* qv, const svec8* mv,
                                           svec8* yf, float& ps_o, float& pq_o) {
  f32x2 psv = {0.f, 0.f}, pqv = {0.f, 0.f};
  #pragma unroll
  for (int ks2 = 0; ks2 < 4; ++ks2) {
    uvec4 qu = __builtin_bit_cast(uvec4, qv[ks2]);
    uvec4 mu = __builtin_bit_cast(uvec4, mv[ks2]);
    uvec4 u;
    #pragma unroll
    for (int p = 0; p < 4; ++p) {
      f32x2 y = __builtin_elementwise_max(up2(qu[p]) + up2(mu[p]), (f32x2){0.f, 0.f});
      psv += y;
      pqv += y * y;
      u[p] = pk2(y[0], y[1]);
    }
    yf[ks2] = __builtin_bit_cast(svec8, u);
  }
  float ps = psv[0] + psv[1], pq = pqv[0] + pqv[1];
  ps += __shfl_xor(ps, 16, 64); pq += __shfl_xor(pq, 16, 64);
  ps += __shfl_xor(ps, 32, 64); pq += __shfl_xor(pq, 32, 64);
  ps_o = ps; pq_o = pq;
}

// ---------------- edge MLP: EG=2, W2' in LDS, nf-split (halved AGPR footprint) ----------
__global__ __launch_bounds__(256, 3) void edge_mlp_kernel(
    const short* __restrict__ qwt, const short* __restrict__ mwt,
    const int* __restrict__ rowi, const int* __restrict__ coli,
    const short* __restrict__ w2p,
    const float* __restrict__ s2v, const float* __restrict__ b2pv,
    const float* __restrict__ gwv, const float* __restrict__ consts,
    float* __restrict__ hout, int E)
{
  __shared__ short w2s[16384];   // 32 KB: all W2' fragments

  const int tid  = threadIdx.x;
  const int wv   = tid >> 6;
  const int lane = tid & 63;
  const int g    = lane >> 4;
  const int l16  = lane & 15;

  // bijective XCD-aware block swizzle (m204)
  const int nb  = gridDim.x;
  const int q8  = nb >> 3, r8 = nb & 7;
  const int xcd = blockIdx.x & 7, sub = blockIdx.x >> 3;
  const int bid = (xcd < r8 ? xcd * (q8 + 1) : r8 * (q8 + 1) + (xcd - r8) * q8) + sub;

  // stage W2' fragments (linear copy)
  #pragma unroll
  for (int it = 0; it < 8; ++it) {
    int o = (it * 256 + tid) * 8;    // shorts
    *(f32x4*)(w2s + o) = *(const f32x4*)(w2p + o);
  }
  __syncthreads();

  const int eb = bid * 128 + wv * 32;
  const int e0 = eb + l16, e1 = eb + 16 + l16;
  const bool v0 = (e0 < E), v1 = (e1 < E);
  const int ee0 = v0 ? e0 : 0, ee1 = v1 ? e1 : 0;
  const short* q0 = qwt + (size_t)rowi[ee0] * 128 + g * 8;
  const short* m0 = mwt + (size_t)coli[ee0] * 128 + g * 8;
  const short* q1 = qwt + (size_t)rowi[ee1] * 128 + g * 8;
  const short* m1 = mwt + (size_t)coli[ee1] * 128 + g * 8;

  // issue all 16 gathers up front
  svec8 qv0[4], mv0[4], qv1[4], mv1[4];
  #pragma unroll
  for (int ks2 = 0; ks2 < 4; ++ks2) {
    qv0[ks2] = *(const svec8*)(q0 + ks2 * 32);
    mv0[ks2] = *(const svec8*)(m0 + ks2 * 32);
    qv1[ks2] = *(const svec8*)(q1 + ks2 * 32);
    mv1[ks2] = *(const svec8*)(m1 + ks2 * 32);
  }

  svec8 yf0[4], yf1[4];
  float ps0, pq0, ps1, pq1;
  relu_stats(qv0, mv0, yf0, ps0, pq0);
  relu_stats(qv1, mv1, yf1, ps1, pq1);
  float mu1_0   = ps0 * (1.f / 128.f);
  float rstd1_0 = rsqrtf(fmaxf(pq0 * (1.f / 128.f) - mu1_0 * mu1_0, 0.f) + LN_EPS);
  float mu1_1   = ps1 * (1.f / 128.f);
  float rstd1_1 = rsqrtf(fmaxf(pq1 * (1.f / 128.f) - mu1_1 * mu1_1, 0.f) + LN_EPS);
  float nmu0 = -rstd1_0 * mu1_0;
  float nmu1 = -rstd1_1 * mu1_1;

  // running epilogue stats carried across the two nf-halves
  f32x2 Aps = {0.f,0.f}, Apq = {0.f,0.f}, Apw = {0.f,0.f};
  f32x2 Bps = {0.f,0.f}, Bpq = {0.f,0.f}, Bpw = {0.f,0.f};

  #pragma unroll
  for (int half = 0; half < 2; ++half) {
    const int nfb = half * 4;
    f32x4 acc2a[4], acc2b[4];
    #pragma unroll
    for (int nf = 0; nf < 4; ++nf) { f32x4 z = {0.f,0.f,0.f,0.f}; acc2a[nf] = z; acc2b[nf] = z; }
    __builtin_amdgcn_s_setprio(1);
    #pragma unroll
    for (int ks2 = 0; ks2 < 4; ++ks2) {
      #pragma unroll
      for (int nf = 0; nf < 4; ++nf) {
        svec8 w = *(const svec8*)(w2s + (((ks2 * 8 + nfb + nf) * 64 + lane) << 3));
        acc2a[nf] = mfma16(w, yf0[ks2], acc2a[nf]);
        acc2b[nf] = mfma16(w, yf1[ks2], acc2b[nf]);
      }
    }
    __builtin_amdgcn_s_setprio(0);
    // partial folded epilogue for this nf-half
    #pragma unroll
    for (int nf = 0; nf < 4; ++nf) {
      f32x4 s2 = *(const f32x4*)(s2v  + (nfb + nf) * 16 + g * 4);
      f32x4 bb = *(const f32x4*)(b2pv + (nfb + nf) * 16 + g * 4);
      f32x4 gw = *(const f32x4*)(gwv  + (nfb + nf) * 16 + g * 4);
      #pragma unroll
      for (int p = 0; p < 2; ++p) {
        f32x2 s2p = { s2[2*p], s2[2*p+1] };
        f32x2 bbp = { bb[2*p], bb[2*p+1] };
        f32x2 gwp = { gw[2*p], gw[2*p+1] };
        f32x2 aa  = { acc2a[nf][2*p], acc2a[nf][2*p+1] };
        f32x2 ab  = { acc2b[nf][2*p], acc2b[nf][2*p+1] };
        f32x2 ha = (f32x2){rstd1_0, rstd1_0} * aa + ((f32x2){nmu0, nmu0} * s2p + bbp);
        f32x2 hb = (f32x2){rstd1_1, rstd1_1} * ab + ((f32x2){nmu1, nmu1} * s2p + bbp);
        f32x2 ya = __builtin_elementwise_max(ha, (f32x2){0.f, 0.f});
        f32x2 yb = __builtin_elementwise_max(hb, (f32x2){0.f, 0.f});
        Aps += ya; Apq += ya * ya; Apw += ya * gwp;
        Bps += yb; Bpq += yb * yb; Bpw += yb * gwp;
      }
    }
  }

  float Sgw = consts[0], cb = consts[1];
  float ps2a = Aps[0] + Aps[1], pq2a = Apq[0] + Apq[1], pw2a = Apw[0] + Apw[1];
  float ps2b = Bps[0] + Bps[1], pq2b = Bpq[0] + Bpq[1], pw2b = Bpw[0] + Bpw[1];
  ps2a += __shfl_xor(ps2a, 16, 64); pq2a += __shfl_xor(pq2a, 16, 64); pw2a += __shfl_xor(pw2a, 16, 64);
  ps2a += __shfl_xor(ps2a, 32, 64); pq2a += __shfl_xor(pq2a, 32, 64); pw2a += __shfl_xor(pw2a, 32, 64);
  ps2b += __shfl_xor(ps2b, 16, 64); pq2b += __shfl_xor(pq2b, 16, 64); pw2b += __shfl_xor(pw2b, 16, 64);
  ps2b += __shfl_xor(ps2b, 32, 64); pq2b += __shfl_xor(pq2b, 32, 64); pw2b += __shfl_xor(pw2b, 32, 64);
  {
    float mu2 = ps2a * (1.f / 128.f);
    float var2 = fmaxf(pq2a * (1.f / 128.f) - mu2 * mu2, 0.f);
    float rstd2 = rsqrtf(var2 + LN_EPS);
    float p3 = fmaf(rstd2, pw2a - mu2 * Sgw, cb);
    if (lane < 16 && v0) hout[e0] = tanhf(p3);
  }
  {
    float mu2 = ps2b * (1.f / 128.f);
    float var2 = fmaxf(pq2b * (1.f / 128.f) - mu2 * mu2, 0.f);
    float rstd2 = rsqrtf(var2 + LN_EPS);
    float p3 = fmaf(rstd2, pw2b - mu2 * Sgw, cb);
    if (lane < 16 && v1) hout[e1] = tanhf(p3);
  }
}

// ---------------- segment sum: full wave per node, 8 edges in flight ----------------
__global__ __launch_bounds__(256) void segsum_kernel(
    const int* __restrict__ off, const int* __restrict__ coli,
    const float* __restrict__ hbuf, const short* __restrict__ mhb,
    float* __restrict__ out, int N)
{
  int wv = threadIdx.x >> 6, lane = threadIdx.x & 63;
  int i = blockIdx.x * 4 + wv;
  if (i >= N) return;
  int s = __builtin_amdgcn_readfirstlane(off[i]);
  int e = __builtin_amdgcn_readfirstlane(off[i + 1]);
  f32x2 acc = {0.f, 0.f};
  int k = s;
  for (; k + 8 <= e; k += 8) {
    float h[8]; unsigned w[8];
    #pragma unroll
    for (int u = 0; u < 8; ++u) {
      h[u] = hbuf[k + u];
      w[u] = *(const unsigned*)(mhb + (size_t)coli[k + u] * 128 + lane * 2);
    }
    #pragma unroll
    for (int u = 0; u < 8; ++u)
      acc += (f32x2){h[u], h[u]} * up2(w[u]);
  }
  for (; k < e; ++k) {
    float h = hbuf[k];
    unsigned w = *(const unsigned*)(mhb + (size_t)coli[k] * 128 + lane * 2);
    acc += (f32x2){h, h} * up2(w);
  }
  *(f32x2*)(out + (size_t)i * 128 + lane * 2) = acc;
}

extern "C" void kernel_launch(void* const* d_in, const int* in_sizes, int n_in,
                              void* d_out, int out_size, void* d_ws, size_t ws_size,
                              hipStream_t stream) {
  const float* query = (const float*)d_in[0];
  const float* mem   = (const float*)d_in[1];
  const int*   row   = (const int*)d_in[2];
  const int*   col   = (const int*)d_in[3];
  const float* pW1 = (const float*)d_in[4];  const float* pb1 = (const float*)d_in[5];
  const float* pW2 = (const float*)d_in[6];  const float* pb2 = (const float*)d_in[7];
  const float* pW3 = (const float*)d_in[8];  const float* pb3 = (const float*)d_in[9];
  const float* pg1 = (const float*)d_in[10]; const float* pbe1 = (const float*)d_in[11];
  const float* pg2 = (const float*)d_in[12]; const float* pbe2 = (const float*)d_in[13];
  const float* mW1 = (const float*)d_in[14]; const float* mb1 = (const float*)d_in[15];
  const float* mW2 = (const float*)d_in[16]; const float* mb2 = (const float*)d_in[17];
  const float* mW3 = (const float*)d_in[18]; const float* mb3 = (const float*)d_in[19];
  const float* mg1 = (const float*)d_in[20]; const float* mbe1 = (const float*)d_in[21];
  const float* mg2 = (const float*)d_in[22]; const float* mbe2 = (const float*)d_in[23];

  const int N = in_sizes[0] / 128;
  const int E = in_sizes[2];

  char* ws = (char*)d_ws;
  short* w1qp = (short*)(ws + 0);        // 32768 B
  short* w1mp = (short*)(ws + 32768);    // 32768 B
  short* w2p  = (short*)(ws + 65536);    // 32768 B (scaled by g1)
  short* mw1p = (short*)(ws + 98304);    // 32768 B
  short* mw2p = (short*)(ws + 131072);   // 32768 B
  short* mw3p = (short*)(ws + 163840);   // 32768 B
  float* s2v  = (float*)(ws + 196608);   // 512 B
  float* b2pv = (float*)(ws + 197120);   // 512 B
  float* gwv  = (float*)(ws + 197632);   // 512 B
  float* cons = (float*)(ws + 198144);   // 64 B
  int*   offs = (int*)(ws + 198208);     // (N+1)*4
  size_t o = 198208 + (((size_t)(N + 1) * 4 + 255) / 256) * 256;
  short* qwt  = (short*)(ws + o);  o += (size_t)N * 128 * 2;   // bf16 q@W1t + b1
  short* mwt  = (short*)(ws + o);  o += (size_t)N * 128 * 2;   // bf16 m@W1b
  short* mhb  = (short*)(ws + o);  o += (size_t)N * 128 * 2;   // bf16 mem_head
  float* hbuf = (float*)(ws + o);  o += (size_t)E * 4;

  if (ws_size < o) return;

  const int nboff = (N + 1 + 255) / 256;
  setup_kernel<<<384 + nboff + 1, 256, 0, stream>>>(
      pW1, pW2, pg1, mW1, mW2, mW3, w1qp, w1mp, w2p, mw1p, mw2p, mw3p,
      row, E, N, offs,
      pg1, pbe1, pb2, pg2, pW3, pbe2, pb3, s2v, b2pv, gwv, cons, nboff);

  const int nbm = (N + 63) / 64;
  node_kernel<<<2 * nbm, 256, 0, stream>>>(
      mem, query, mw1p, mw2p, mw3p, w1mp, w1qp,
      mb1, mb2, mb3, mg1, mbe1, mg2, mbe2, pb1,
      mhb, mwt, qwt, N, nbm);

  edge_mlp_kernel<<<(E + 127) / 128, 256, 0, stream>>>(
      qwt, mwt, row, col, w2p, s2v, b2pv, gwv, cons, hbuf, E);

  segsum_kernel<<<(N + 3) / 4, 256, 0, stream>>>(offs, col, hbuf, mhb, (float*)d_out, N);
}

// Round 14
// 164.424 us; speedup vs baseline: 2.4607x; 1.0055x over previous
//
#include <hip/hip_runtime.h>
#include <hip/hip_bf16.h>

typedef __attribute__((ext_vector_type(8))) short  svec8;
typedef __attribute__((ext_vector_type(4))) short  svec4;
typedef __attribute__((ext_vector_type(8))) __bf16 bfvec8;
typedef __attribute__((ext_vector_type(4))) float  f32x4;
typedef __attribute__((ext_vector_type(2))) float  f32x2;
typedef __attribute__((ext_vector_type(4))) unsigned uvec4;

#define LN_EPS 1e-3f

__device__ __forceinline__ short f2bf(float f) {
  union { float f; unsigned u; } v; v.f = f;
  unsigned u = v.u;
  u += 0x7fff + ((u >> 16) & 1);   // round-to-nearest-even
  return (short)(u >> 16);
}

__device__ __forceinline__ unsigned pk2(float a, float b) {
  unsigned short ua = __builtin_bit_cast(unsigned short, (__bf16)a);
  unsigned short ub = __builtin_bit_cast(unsigned short, (__bf16)b);
  return (unsigned)ua | ((unsigned)ub << 16);
}

__device__ __forceinline__ f32x2 up2(unsigned w) {   // u32 of 2 bf16 -> f32x2
  f32x2 r;
  r[0] = __builtin_bit_cast(float, w << 16);
  r[1] = __builtin_bit_cast(float, w & 0xffff0000u);
  return r;
}

__device__ __forceinline__ f32x4 mfma16(svec8 a, svec8 b, f32x4 c) {
  return __builtin_amdgcn_mfma_f32_16x16x32_bf16(
      __builtin_bit_cast(bfvec8, a), __builtin_bit_cast(bfvec8, b), c, 0, 0, 0);
}

// ================= setup: pack 6 weights + CSR offsets + folded constants, ONE launch ====
__global__ __launch_bounds__(256) void setup_kernel(
    const float* __restrict__ pW1, const float* __restrict__ pW2,
    const float* __restrict__ pg1,
    const float* __restrict__ mW1, const float* __restrict__ mW2,
    const float* __restrict__ mW3,
    short* __restrict__ w1qp, short* __restrict__ w1mp,
    short* __restrict__ w2p,  short* __restrict__ mw1p,
    short* __restrict__ mw2p, short* __restrict__ mw3p,
    const int* __restrict__ row, int E, int N, int* __restrict__ off,
    const float* __restrict__ g1, const float* __restrict__ be1,
    const float* __restrict__ b2, const float* __restrict__ g2,
    const float* __restrict__ w3, const float* __restrict__ be2,
    const float* __restrict__ b3,
    float* __restrict__ s2, float* __restrict__ b2pv,
    float* __restrict__ gw, float* __restrict__ consts, int nboff)
{
  const int b = blockIdx.x;
  const int tid = threadIdx.x;
  if (b < 384) {                       // ---- pack weights: 6 * 16384 elems ----
    int idx = b * 256 + tid;
    int which = idx >> 14, p = idx & 16383;
    int j = p & 7, lane = (p >> 3) & 63, t = p >> 9;
    int nf = t & 7, ks = t >> 3;
    int k = ks * 32 + (lane >> 4) * 8 + j;
    int n = nf * 16 + (lane & 15);
    const float* src; short* dst; float scale = 1.f;
    switch (which) {
      case 0:  src = pW1;         dst = w1qp; break;
      case 1:  src = pW1 + 16384; dst = w1mp; break;
      case 2:  src = pW2;         dst = w2p; scale = pg1[k]; break;
      case 3:  src = mW1;         dst = mw1p; break;
      case 4:  src = mW2;         dst = mw2p; break;
      default: src = mW3;         dst = mw3p; break;
    }
    dst[p] = f2bf(scale * src[k * 128 + n]);
  } else if (b < 384 + nboff) {        // ---- CSR offsets via binary search ----
    int i = (b - 384) * 256 + tid;
    if (i > N) return;
    int lo = 0, hi = E;
    while (lo < hi) { int mid = (lo + hi) >> 1; if (row[mid] < i) lo = mid + 1; else hi = mid; }
    off[i] = lo;
  } else {                             // ---- folded constants ----
    __shared__ float tmp[256];
    int n = tid;
    if (n < 128) {
      float s = 0.f, bb = 0.f;
      for (int k = 0; k < 128; ++k) {
        float w = pW2[k * 128 + n];
        s  = fmaf(g1[k],  w, s);
        bb = fmaf(be1[k], w, bb);
      }
      s2[n]   = s;
      b2pv[n] = bb + b2[n];
      float g = g2[n] * w3[n];
      gw[n] = g;
      tmp[n]       = g;
      tmp[128 + n] = be2[n] * w3[n];
    }
    __syncthreads();
    if (n == 0) {
      float a = 0.f, c = 0.f;
      for (int i = 0; i < 128; ++i) { a += tmp[i]; c += tmp[128 + i]; }
      consts[0] = a;
      consts[1] = c + b3[0];
    }
  }
}

// ======== node kernel v2: wave-autonomous — each wave owns 16 rows x all 128 cols ========
__global__ __launch_bounds__(256) void node_kernel(
    const float* __restrict__ mem, const float* __restrict__ query,
    const short* __restrict__ w1p, const short* __restrict__ w2p, const short* __restrict__ w3p,
    const short* __restrict__ wmp, const short* __restrict__ wqp,
    const float* __restrict__ b1v, const float* __restrict__ b2v, const float* __restrict__ b3v,
    const float* __restrict__ g1v, const float* __restrict__ be1v,
    const float* __restrict__ g2v, const float* __restrict__ be2v,
    const float* __restrict__ pb1,
    short* __restrict__ mhb, short* __restrict__ mwt, short* __restrict__ qwt,
    int N, int nbm)
{
  __shared__ char Hs[4][4096];   // wave-private 16x128 bf16 slices (swizzled)

  const int tid  = threadIdx.x;
  const int wv   = tid >> 6;
  const int lane = tid & 63;
  const int g    = lane >> 4;
  const int l16  = lane & 15;
  const bool is_mem = (blockIdx.x < nbm);
  const int r0   = (is_mem ? blockIdx.x : blockIdx.x - nbm) * 64 + wv * 16;
  const float* src = is_mem ? mem : query;

  int grow = r0 + l16; if (grow >= N) grow = N - 1;
  const float* xrow = src + (size_t)grow * 128 + g * 8;
  svec8 xf[4];
  #pragma unroll
  for (int ks = 0; ks < 4; ++ks) {
    f32x4 a = *(const f32x4*)(xrow + ks * 32);
    f32x4 b = *(const f32x4*)(xrow + ks * 32 + 4);
    uvec4 u;
    u[0] = pk2(a[0], a[1]); u[1] = pk2(a[2], a[3]);
    u[2] = pk2(b[0], b[1]); u[3] = pk2(b[2], b[3]);
    xf[ks] = __builtin_bit_cast(svec8, u);
  }

  if (!is_mem) {
    f32x4 acc[8];
    #pragma unroll
    for (int nf = 0; nf < 8; ++nf) { f32x4 z = {0.f,0.f,0.f,0.f}; acc[nf] = z; }
    #pragma unroll
    for (int ks = 0; ks < 4; ++ks)
      #pragma unroll
      for (int nf = 0; nf < 8; ++nf) {
        svec8 bw = *(const svec8*)(wqp + (((ks * 8 + nf) * 64 + lane) << 3));
        acc[nf] = mfma16(xf[ks], bw, acc[nf]);
      }
    #pragma unroll
    for (int nf = 0; nf < 8; ++nf) {
      float bi = pb1[nf * 16 + l16];
      #pragma unroll
      for (int r = 0; r < 4; ++r) {
        int gr = r0 + g * 4 + r;
        if (gr < N) qwt[(size_t)gr * 128 + nf * 16 + l16] = f2bf(acc[nf][r] + bi);
      }
    }
    return;
  }

  f32x4 acc[8], accm[8];
  #pragma unroll
  for (int nf = 0; nf < 8; ++nf) { f32x4 z = {0.f,0.f,0.f,0.f}; acc[nf] = z; accm[nf] = z; }
  #pragma unroll
  for (int ks = 0; ks < 4; ++ks)
    #pragma unroll
    for (int nf = 0; nf < 8; ++nf) {
      svec8 bw = *(const svec8*)(w1p + (((ks * 8 + nf) * 64 + lane) << 3));
      svec8 bm = *(const svec8*)(wmp + (((ks * 8 + nf) * 64 + lane) << 3));
      acc[nf]  = mfma16(xf[ks], bw, acc[nf]);
      accm[nf] = mfma16(xf[ks], bm, accm[nf]);
    }
  #pragma unroll
  for (int nf = 0; nf < 8; ++nf)
    #pragma unroll
    for (int r = 0; r < 4; ++r) {
      int gr = r0 + g * 4 + r;
      if (gr < N) mwt[(size_t)gr * 128 + nf * 16 + l16] = f2bf(accm[nf][r]);
    }

  char* slice = Hs[wv];

  float ps[4] = {0,0,0,0}, pq[4] = {0,0,0,0};
  #pragma unroll
  for (int nf = 0; nf < 8; ++nf) {
    float bi = b1v[nf * 16 + l16];
    #pragma unroll
    for (int r = 0; r < 4; ++r) {
      float y = fmaxf(acc[nf][r] + bi, 0.f);
      acc[nf][r] = y;
      ps[r] += y;
      pq[r] = fmaf(y, y, pq[r]);
    }
  }
  #pragma unroll
  for (int mk = 1; mk <= 8; mk <<= 1)
    #pragma unroll
    for (int r = 0; r < 4; ++r) {
      ps[r] += __shfl_xor(ps[r], mk, 64);
      pq[r] += __shfl_xor(pq[r], mk, 64);
    }
  #pragma unroll
  for (int r = 0; r < 4; ++r) {
    float mu = ps[r] * (1.f / 128.f);
    float var = fmaxf(pq[r] * (1.f / 128.f) - mu * mu, 0.f);
    float rstd = rsqrtf(var + LN_EPS);
    int rloc = g * 4 + r;
    #pragma unroll
    for (int nf = 0; nf < 8; ++nf) {
      float ga = g1v[nf * 16 + l16], bb = be1v[nf * 16 + l16];
      float z = (acc[nf][r] - mu) * rstd * ga + bb;
      int byt = (rloc * 256 + (nf * 16 + l16) * 2) ^ ((rloc & 7) << 4);
      *(short*)(slice + byt) = f2bf(z);
    }
  }

  svec8 hf[4];
  #pragma unroll
  for (int ks = 0; ks < 4; ++ks) {
    int byt = (l16 * 256 + (ks * 32 + g * 8) * 2) ^ ((l16 & 7) << 4);
    hf[ks] = *(const svec8*)(slice + byt);
  }
  f32x4 acc2[8];
  #pragma unroll
  for (int nf = 0; nf < 8; ++nf) { f32x4 z = {0.f,0.f,0.f,0.f}; acc2[nf] = z; }
  #pragma unroll
  for (int ks = 0; ks < 4; ++ks)
    #pragma unroll
    for (int nf = 0; nf < 8; ++nf) {
      svec8 bw = *(const svec8*)(w2p + (((ks * 8 + nf) * 64 + lane) << 3));
      acc2[nf] = mfma16(hf[ks], bw, acc2[nf]);
    }

  #pragma unroll
  for (int r = 0; r < 4; ++r) { ps[r] = 0.f; pq[r] = 0.f; }
  #pragma unroll
  for (int nf = 0; nf < 8; ++nf) {
    float bi = b2v[nf * 16 + l16];
    #pragma unroll
    for (int r = 0; r < 4; ++r) {
      float y = fmaxf(acc2[nf][r] + bi, 0.f);
      acc2[nf][r] = y;
      ps[r] += y;
      pq[r] = fmaf(y, y, pq[r]);
    }
  }
  #pragma unroll
  for (int mk = 1; mk <= 8; mk <<= 1)
    #pragma unroll
    for (int r = 0; r < 4; ++r) {
      ps[r] += __shfl_xor(ps[r], mk, 64);
      pq[r] += __shfl_xor(pq[r], mk, 64);
    }
  #pragma unroll
  for (int r = 0; r < 4; ++r) {
    float mu = ps[r] * (1.f / 128.f);
    float var = fmaxf(pq[r] * (1.f / 128.f) - mu * mu, 0.f);
    float rstd = rsqrtf(var + LN_EPS);
    int rloc = g * 4 + r;
    #pragma unroll
    for (int nf = 0; nf < 8; ++nf) {
      float ga = g2v[nf * 16 + l16], bb = be2v[nf * 16 + l16];
      float z = (acc2[nf][r] - mu) * rstd * ga + bb;
      int byt = (rloc * 256 + (nf * 16 + l16) * 2) ^ ((rloc & 7) << 4);
      *(short*)(slice + byt) = f2bf(z);
    }
  }

  #pragma unroll
  for (int ks = 0; ks < 4; ++ks) {
    int byt = (l16 * 256 + (ks * 32 + g * 8) * 2) ^ ((l16 & 7) << 4);
    hf[ks] = *(const svec8*)(slice + byt);
  }
  f32x4 acc3[8];
  #pragma unroll
  for (int nf = 0; nf < 8; ++nf) { f32x4 z = {0.f,0.f,0.f,0.f}; acc3[nf] = z; }
  #pragma unroll
  for (int ks = 0; ks < 4; ++ks)
    #pragma unroll
    for (int nf = 0; nf < 8; ++nf) {
      svec8 bw = *(const svec8*)(w3p + (((ks * 8 + nf) * 64 + lane) << 3));
      acc3[nf] = mfma16(hf[ks], bw, acc3[nf]);
    }
  #pragma unroll
  for (int nf = 0; nf < 8; ++nf) {
    float bi = b3v[nf * 16 + l16];
    #pragma unroll
    for (int r = 0; r < 4; ++r) {
      int gr = r0 + g * 4 + r;
      if (gr < N) mhb[(size_t)gr * 128 + nf * 16 + l16] = f2bf(acc3[nf][r] + bi);
    }
  }
}

// ---- relu(q+m) with packed f32; emits B-frags + sum/sumsq ----
__device__ __forceinline__ void relu_stats(const svec8* qv, const svec8* mv,
                                           svec8* yf, float& ps_o, float& pq_o) {
  f32x2 psv = {0.f, 0.f}, pqv = {0.f, 0.f};
  #pragma unroll
  for (int ks2 = 0; ks2 < 4; ++ks2) {
    uvec4 qu = __builtin_bit_cast(uvec4, qv[ks2]);
    uvec4 mu = __builtin_bit_cast(uvec4, mv[ks2]);
    uvec4 u;
    #pragma unroll
    for (int p = 0; p < 4; ++p) {
      f32x2 y = __builtin_elementwise_max(up2(qu[p]) + up2(mu[p]), (f32x2){0.f, 0.f});
      psv += y;
      pqv += y * y;
      u[p] = pk2(y[0], y[1]);
    }
    yf[ks2] = __builtin_bit_cast(svec8, u);
  }
  float ps = psv[0] + psv[1], pq = pqv[0] + pqv[1];
  ps += __shfl_xor(ps, 16, 64); pq += __shfl_xor(pq, 16, 64);
  ps += __shfl_xor(ps, 32, 64); pq += __shfl_xor(pq, 32, 64);
  ps_o = ps; pq_o = pq;
}

// ---------------- edge MLP: EG=2, W2' in LDS, nf-split, 4 blocks/CU ----------
__global__ __launch_bounds__(256, 4) void edge_mlp_kernel(
    const short* __restrict__ qwt, const short* __restrict__ mwt,
    const int* __restrict__ rowi, const int* __restrict__ coli,
    const short* __restrict__ w2p,
    const float* __restrict__ s2v, const float* __restrict__ b2pv,
    const float* __restrict__ gwv, const float* __restrict__ consts,
    float* __restrict__ hout, int E)
{
  __shared__ short w2s[16384];   // 32 KB: all W2' fragments

  const int tid  = threadIdx.x;
  const int wv   = tid >> 6;
  const int lane = tid & 63;
  const int g    = lane >> 4;
  const int l16  = lane & 15;

  // bijective XCD-aware block swizzle (m204)
  const int nb  = gridDim.x;
  const int q8  = nb >> 3, r8 = nb & 7;
  const int xcd = blockIdx.x & 7, sub = blockIdx.x >> 3;
  const int bid = (xcd < r8 ? xcd * (q8 + 1) : r8 * (q8 + 1) + (xcd - r8) * q8) + sub;

  // stage W2' fragments (linear copy)
  #pragma unroll
  for (int it = 0; it < 8; ++it) {
    int o = (it * 256 + tid) * 8;    // shorts
    *(f32x4*)(w2s + o) = *(const f32x4*)(w2p + o);
  }
  __syncthreads();

  const int eb = bid * 128 + wv * 32;
  const int e0 = eb + l16, e1 = eb + 16 + l16;
  const bool v0 = (e0 < E), v1 = (e1 < E);
  const int ee0 = v0 ? e0 : 0, ee1 = v1 ? e1 : 0;
  const short* q0 = qwt + (size_t)rowi[ee0] * 128 + g * 8;
  const short* m0 = mwt + (size_t)coli[ee0] * 128 + g * 8;
  const short* q1 = qwt + (size_t)rowi[ee1] * 128 + g * 8;
  const short* m1 = mwt + (size_t)coli[ee1] * 128 + g * 8;

  // issue all 16 gathers up front
  svec8 qv0[4], mv0[4], qv1[4], mv1[4];
  #pragma unroll
  for (int ks2 = 0; ks2 < 4; ++ks2) {
    qv0[ks2] = *(const svec8*)(q0 + ks2 * 32);
    mv0[ks2] = *(const svec8*)(m0 + ks2 * 32);
    qv1[ks2] = *(const svec8*)(q1 + ks2 * 32);
    mv1[ks2] = *(const svec8*)(m1 + ks2 * 32);
  }

  svec8 yf0[4], yf1[4];
  float ps0, pq0, ps1, pq1;
  relu_stats(qv0, mv0, yf0, ps0, pq0);
  relu_stats(qv1, mv1, yf1, ps1, pq1);
  float mu1_0   = ps0 * (1.f / 128.f);
  float rstd1_0 = rsqrtf(fmaxf(pq0 * (1.f / 128.f) - mu1_0 * mu1_0, 0.f) + LN_EPS);
  float mu1_1   = ps1 * (1.f / 128.f);
  float rstd1_1 = rsqrtf(fmaxf(pq1 * (1.f / 128.f) - mu1_1 * mu1_1, 0.f) + LN_EPS);
  float nmu0 = -rstd1_0 * mu1_0;
  float nmu1 = -rstd1_1 * mu1_1;

  // running epilogue stats carried across the two nf-halves
  f32x2 Aps = {0.f,0.f}, Apq = {0.f,0.f}, Apw = {0.f,0.f};
  f32x2 Bps = {0.f,0.f}, Bpq = {0.f,0.f}, Bpw = {0.f,0.f};

  #pragma unroll
  for (int half = 0; half < 2; ++half) {
    const int nfb = half * 4;
    f32x4 acc2a[4], acc2b[4];
    #pragma unroll
    for (int nf = 0; nf < 4; ++nf) { f32x4 z = {0.f,0.f,0.f,0.f}; acc2a[nf] = z; acc2b[nf] = z; }
    __builtin_amdgcn_s_setprio(1);
    #pragma unroll
    for (int ks2 = 0; ks2 < 4; ++ks2) {
      #pragma unroll
      for (int nf = 0; nf < 4; ++nf) {
        svec8 w = *(const svec8*)(w2s + (((ks2 * 8 + nfb + nf) * 64 + lane) << 3));
        acc2a[nf] = mfma16(w, yf0[ks2], acc2a[nf]);
        acc2b[nf] = mfma16(w, yf1[ks2], acc2b[nf]);
      }
    }
    __builtin_amdgcn_s_setprio(0);
    // partial folded epilogue for this nf-half
    #pragma unroll
    for (int nf = 0; nf < 4; ++nf) {
      f32x4 s2 = *(const f32x4*)(s2v  + (nfb + nf) * 16 + g * 4);
      f32x4 bb = *(const f32x4*)(b2pv + (nfb + nf) * 16 + g * 4);
      f32x4 gw = *(const f32x4*)(gwv  + (nfb + nf) * 16 + g * 4);
      #pragma unroll
      for (int p = 0; p < 2; ++p) {
        f32x2 s2p = { s2[2*p], s2[2*p+1] };
        f32x2 bbp = { bb[2*p], bb[2*p+1] };
        f32x2 gwp = { gw[2*p], gw[2*p+1] };
        f32x2 aa  = { acc2a[nf][2*p], acc2a[nf][2*p+1] };
        f32x2 ab  = { acc2b[nf][2*p], acc2b[nf][2*p+1] };
        f32x2 ha = (f32x2){rstd1_0, rstd1_0} * aa + ((f32x2){nmu0, nmu0} * s2p + bbp);
        f32x2 hb = (f32x2){rstd1_1, rstd1_1} * ab + ((f32x2){nmu1, nmu1} * s2p + bbp);
        f32x2 ya = __builtin_elementwise_max(ha, (f32x2){0.f, 0.f});
        f32x2 yb = __builtin_elementwise_max(hb, (f32x2){0.f, 0.f});
        Aps += ya; Apq += ya * ya; Apw += ya * gwp;
        Bps += yb; Bpq += yb * yb; Bpw += yb * gwp;
      }
    }
  }

  float Sgw = consts[0], cb = consts[1];
  float ps2a = Aps[0] + Aps[1], pq2a = Apq[0] + Apq[1], pw2a = Apw[0] + Apw[1];
  float ps2b = Bps[0] + Bps[1], pq2b = Bpq[0] + Bpq[1], pw2b = Bpw[0] + Bpw[1];
  ps2a += __shfl_xor(ps2a, 16, 64); pq2a += __shfl_xor(pq2a, 16, 64); pw2a += __shfl_xor(pw2a, 16, 64);
  ps2a += __shfl_xor(ps2a, 32, 64); pq2a += __shfl_xor(pq2a, 32, 64); pw2a += __shfl_xor(pw2a, 32, 64);
  ps2b += __shfl_xor(ps2b, 16, 64); pq2b += __shfl_xor(pq2b, 16, 64); pw2b += __shfl_xor(pw2b, 16, 64);
  ps2b += __shfl_xor(ps2b, 32, 64); pq2b += __shfl_xor(pq2b, 32, 64); pw2b += __shfl_xor(pw2b, 32, 64);
  {
    float mu2 = ps2a * (1.f / 128.f);
    float var2 = fmaxf(pq2a * (1.f / 128.f) - mu2 * mu2, 0.f);
    float rstd2 = rsqrtf(var2 + LN_EPS);
    float p3 = fmaf(rstd2, pw2a - mu2 * Sgw, cb);
    if (lane < 16 && v0) hout[e0] = tanhf(p3);
  }
  {
    float mu2 = ps2b * (1.f / 128.f);
    float var2 = fmaxf(pq2b * (1.f / 128.f) - mu2 * mu2, 0.f);
    float rstd2 = rsqrtf(var2 + LN_EPS);
    float p3 = fmaf(rstd2, pw2b - mu2 * Sgw, cb);
    if (lane < 16 && v1) hout[e1] = tanhf(p3);
  }
}

// ---------------- segment sum: full wave per node, 16 edges in flight ----------------
__global__ __launch_bounds__(256) void segsum_kernel(
    const int* __restrict__ off, const int* __restrict__ coli,
    const float* __restrict__ hbuf, const short* __restrict__ mhb,
    float* __restrict__ out, int N)
{
  int wv = threadIdx.x >> 6, lane = threadIdx.x & 63;
  int i = blockIdx.x * 4 + wv;
  if (i >= N) return;
  int s = __builtin_amdgcn_readfirstlane(off[i]);
  int e = __builtin_amdgcn_readfirstlane(off[i + 1]);
  f32x2 acc = {0.f, 0.f};
  int k = s;
  for (; k + 16 <= e; k += 16) {
    float h[16]; unsigned w[16];
    #pragma unroll
    for (int u = 0; u < 16; ++u) {
      h[u] = hbuf[k + u];
      w[u] = *(const unsigned*)(mhb + (size_t)coli[k + u] * 128 + lane * 2);
    }
    #pragma unroll
    for (int u = 0; u < 16; ++u)
      acc += (f32x2){h[u], h[u]} * up2(w[u]);
  }
  for (; k + 4 <= e; k += 4) {
    float h[4]; unsigned w[4];
    #pragma unroll
    for (int u = 0; u < 4; ++u) {
      h[u] = hbuf[k + u];
      w[u] = *(const unsigned*)(mhb + (size_t)coli[k + u] * 128 + lane * 2);
    }
    #pragma unroll
    for (int u = 0; u < 4; ++u)
      acc += (f32x2){h[u], h[u]} * up2(w[u]);
  }
  for (; k < e; ++k) {
    float h = hbuf[k];
    unsigned w = *(const unsigned*)(mhb + (size_t)coli[k] * 128 + lane * 2);
    acc += (f32x2){h, h} * up2(w);
  }
  *(f32x2*)(out + (size_t)i * 128 + lane * 2) = acc;
}

extern "C" void kernel_launch(void* const* d_in, const int* in_sizes, int n_in,
                              void* d_out, int out_size, void* d_ws, size_t ws_size,
                              hipStream_t stream) {
  const float* query = (const float*)d_in[0];
  const float* mem   = (const float*)d_in[1];
  const int*   row   = (const int*)d_in[2];
  const int*   col   = (const int*)d_in[3];
  const float* pW1 = (const float*)d_in[4];  const float* pb1 = (const float*)d_in[5];
  const float* pW2 = (const float*)d_in[6];  const float* pb2 = (const float*)d_in[7];
  const float* pW3 = (const float*)d_in[8];  const float* pb3 = (const float*)d_in[9];
  const float* pg1 = (const float*)d_in[10]; const float* pbe1 = (const float*)d_in[11];
  const float* pg2 = (const float*)d_in[12]; const float* pbe2 = (const float*)d_in[13];
  const float* mW1 = (const float*)d_in[14]; const float* mb1 = (const float*)d_in[15];
  const float* mW2 = (const float*)d_in[16]; const float* mb2 = (const float*)d_in[17];
  const float* mW3 = (const float*)d_in[18]; const float* mb3 = (const float*)d_in[19];
  const float* mg1 = (const float*)d_in[20]; const float* mbe1 = (const float*)d_in[21];
  const float* mg2 = (const float*)d_in[22]; const float* mbe2 = (const float*)d_in[23];

  const int N = in_sizes[0] / 128;
  const int E = in_sizes[2];

  char* ws = (char*)d_ws;
  short* w1qp = (short*)(ws + 0);        // 32768 B
  short* w1mp = (short*)(ws + 32768);    // 32768 B
  short* w2p  = (short*)(ws + 65536);    // 32768 B (scaled by g1)
  short* mw1p = (short*)(ws + 98304);    // 32768 B
  short* mw2p = (short*)(ws + 131072);   // 32768 B
  short* mw3p = (short*)(ws + 163840);   // 32768 B
  float* s2v  = (float*)(ws + 196608);   // 512 B
  float* b2pv = (float*)(ws + 197120);   // 512 B
  float* gwv  = (float*)(ws + 197632);   // 512 B
  float* cons = (float*)(ws + 198144);   // 64 B
  int*   offs = (int*)(ws + 198208);     // (N+1)*4
  size_t o = 198208 + (((size_t)(N + 1) * 4 + 255) / 256) * 256;
  short* qwt  = (short*)(ws + o);  o += (size_t)N * 128 * 2;   // bf16 q@W1t + b1
  short* mwt  = (short*)(ws + o);  o += (size_t)N * 128 * 2;   // bf16 m@W1b
  short* mhb  = (short*)(ws + o);  o += (size_t)N * 128 * 2;   // bf16 mem_head
  float* hbuf = (float*)(ws + o);  o += (size_t)E * 4;

  if (ws_size < o) return;

  const int nboff = (N + 1 + 255) / 256;
  setup_kernel<<<384 + nboff + 1, 256, 0, stream>>>(
      pW1, pW2, pg1, mW1, mW2, mW3, w1qp, w1mp, w2p, mw1p, mw2p, mw3p,
      row, E, N, offs,
      pg1, pbe1, pb2, pg2, pW3, pbe2, pb3, s2v, b2pv, gwv, cons, nboff);

  const int nbm = (N + 63) / 64;
  node_kernel<<<2 * nbm, 256, 0, stream>>>(
      mem, query, mw1p, mw2p, mw3p, w1mp, w1qp,
      mb1, mb2, mb3, mg1, mbe1, mg2, mbe2, pb1,
      mhb, mwt, qwt, N, nbm);

  edge_mlp_kernel<<<(E + 127) / 128, 256, 0, stream>>>(
      qwt, mwt, row, col, w2p, s2v, b2pv, gwv, cons, hbuf, E);

  segsum_kernel<<<(N + 3) / 4, 256, 0, stream>>>(offs, col, hbuf, mhb, (float*)d_out, N);
}